// Round 10
// baseline (651.590 us; speedup 1.0000x reference)
//
#include <hip/hip_runtime.h>
#include <math.h>

#define LREL 0.01f
__device__ __forceinline__ float lrelu(float x) { return x > 0.f ? x : LREL * x; }
__device__ __forceinline__ float fast_tanh(float x) {
    x = fminf(fmaxf(x, -10.f), 10.f);
    float a = __expf(2.f * x);
    return (a - 1.f) / (a + 1.f);
}
__device__ __forceinline__ unsigned short f2bf(float f) {
    unsigned u = __float_as_uint(f);
    unsigned r = u + 0x7FFFu + ((u >> 16) & 1u);
    return (unsigned short)(r >> 16);
}

typedef __attribute__((ext_vector_type(8))) short short8;
typedef __attribute__((ext_vector_type(4))) float f32x4;

// ================= e1: 3->32, 128x128 -> 64x64, 4x4 s2 p1, lrelu (fp32) =================
// grid 1024: n = b&63 ; t = b>>6: rt = t&7 (8 row tiles of 8), cg = t>>3 (2 groups of 16 co)
__global__ void __launch_bounds__(256) conv_e1_t(
    const float* __restrict__ x, const float* __restrict__ w,
    const float* __restrict__ bias, float* __restrict__ out)
{
    __shared__ float lin[3][18][131];
    __shared__ float lw[3][16][16];
    int b = blockIdx.x;
    int n = b & 63, t = b >> 6;
    int rt = t & 7, cg = t >> 3;
    int tid = threadIdx.x;
    int r = tid >> 5, g = tid & 31;
    const float* inp = x + (size_t)n * 3 * 16384;

    for (int i = tid; i < 7020; i += 256) {
        int ci = i / 2340, rr = i % 2340;
        int row = rr / 130, xx = rr % 130;
        int gy = 16 * rt - 1 + row, gx = xx - 1;
        float v = 0.f;
        if (gy >= 0 && gy < 128 && gx >= 0 && gx < 128)
            v = inp[ci * 16384 + gy * 128 + gx];
        lin[ci][row][xx] = v;
    }
    for (int i = tid; i < 768; i += 256) {
        int ci = i >> 8, rr = i & 255, co = rr >> 4, tt = rr & 15;
        lw[ci][co][tt] = w[((cg * 16 + co) * 3 + ci) * 16 + tt];
    }
    __syncthreads();

    float acc[16][2];
    #pragma unroll
    for (int co = 0; co < 16; ++co) { acc[co][0] = acc[co][1] = 0.f; }

    #pragma unroll
    for (int ci = 0; ci < 3; ++ci) {
        float win[4][6];
        #pragma unroll
        for (int ky = 0; ky < 4; ++ky)
            #pragma unroll
            for (int dx = 0; dx < 6; ++dx)
                win[ky][dx] = lin[ci][2 * r + ky][4 * g + dx];
        #pragma unroll
        for (int co = 0; co < 16; ++co) {
            #pragma unroll
            for (int ky = 0; ky < 4; ++ky)
                #pragma unroll
                for (int kx = 0; kx < 4; ++kx) {
                    float wv = lw[ci][co][ky * 4 + kx];
                    acc[co][0] = fmaf(win[ky][kx],     wv, acc[co][0]);
                    acc[co][1] = fmaf(win[ky][kx + 2], wv, acc[co][1]);
                }
        }
    }
    int oy = 8 * rt + r;
    #pragma unroll
    for (int co = 0; co < 16; ++co) {
        float bv = bias[cg * 16 + co];
        float2 v;
        v.x = lrelu(acc[co][0] + bv);
        v.y = lrelu(acc[co][1] + bv);
        *(float2*)(out + ((size_t)(n * 32 + cg * 16 + co) << 12) + oy * 64 + 2 * g) = v;
    }
}

// ================= e2 partial: 32->64, 64x64 -> 32x32, 16-ci halves, no bias/act =================
// grid 1024: n = b&63, ry = (b>>6)&7 (4-row tiles), ch = b>>9 (ci half)
__global__ void __launch_bounds__(256) conv_e2p_k(
    const float* __restrict__ in, const float* __restrict__ w,
    float* __restrict__ outA, float* __restrict__ outB)
{
    __shared__ float lin[4][10][66];
    __shared__ float lw[4][64][16];
    int b = blockIdx.x;
    int n = b & 63, ry = (b >> 6) & 7, ch = b >> 9;
    int tid = threadIdx.x;
    int c = tid & 31, cog = tid >> 5;
    int iy0 = 8 * ry - 1;
    const float* inp = in + (size_t)n * 32 * 4096;
    float* outp = (ch ? outB : outA);

    float acc[8][4];
    #pragma unroll
    for (int q = 0; q < 8; ++q) { acc[q][0]=acc[q][1]=acc[q][2]=acc[q][3]=0.f; }

    for (int cic = 0; cic < 4; ++cic) {
        __syncthreads();
        for (int i = tid; i < 2640; i += 256) {
            int ci = i / 660, rr = i % 660;
            int riy = rr / 66, j = rr % 66;
            int gy = iy0 + riy, gx = j - 1;
            float v = 0.f;
            if (gy >= 0 && gy < 64 && gx >= 0 && gx < 64)
                v = inp[(ch * 16 + cic * 4 + ci) * 4096 + gy * 64 + gx];
            lin[ci][riy][j] = v;
        }
        for (int i = tid; i < 4096; i += 256) {
            int ci = i >> 10, rr = i & 1023, co = rr >> 4, tt = rr & 15;
            lw[ci][co][tt] = w[(co * 32 + ch * 16 + cic * 4 + ci) * 16 + tt];
        }
        __syncthreads();
        #pragma unroll
        for (int ci = 0; ci < 4; ++ci) {
            float win[10][4];
            #pragma unroll
            for (int riy = 0; riy < 10; ++riy)
                #pragma unroll
                for (int q = 0; q < 4; ++q)
                    win[riy][q] = lin[ci][riy][2 * c + q];
            #pragma unroll
            for (int cq = 0; cq < 8; ++cq) {
                const float* wp = lw[ci][cog * 8 + cq];
                #pragma unroll
                for (int r = 0; r < 4; ++r)
                    #pragma unroll
                    for (int ky = 0; ky < 4; ++ky)
                        #pragma unroll
                        for (int kx = 0; kx < 4; ++kx)
                            acc[cq][r] = fmaf(win[2 * r + ky][kx], wp[ky * 4 + kx], acc[cq][r]);
            }
        }
    }
    #pragma unroll
    for (int cq = 0; cq < 8; ++cq) {
        int co = cog * 8 + cq;
        #pragma unroll
        for (int r = 0; r < 4; ++r)
            outp[((size_t)(n * 64 + co) << 10) + (4 * ry + r) * 32 + c] = acc[cq][r];
    }
}

// ================= conv3x3 fp32 (encoder), row-halves; INM: 0 plain, 1 lrelu(A+B+b2) =================
// grid 1024: n = b&63 ; cg = (b>>6)&7 ; h = b>>9 (16-row half)
template<int INM, int ACT, int STATS>
__global__ void __launch_bounds__(256) conv3x3_t(
    const float* __restrict__ inA, const float* __restrict__ inB,
    const float* __restrict__ bias2, const float* __restrict__ w,
    const float* __restrict__ bias, float* __restrict__ out,
    float* __restrict__ psum, float* __restrict__ pss)
{
    __shared__ float lin[8][18][35];
    __shared__ float lw[8][8][9];
    __shared__ float sb[64];
    __shared__ float sS[8][4], sQ[8][4];
    int b = blockIdx.x;
    int n = b & 63, cg = (b >> 6) & 7, h = b >> 9;
    int tid = threadIdx.x;
    int r = tid >> 4, g = tid & 15, c0 = g << 1;
    int lane = tid & 63, wv_id = tid >> 6;
    const float4* inA4 = (const float4*)(inA + (size_t)n * 65536);
    const float4* inB4 = (INM == 1) ? (const float4*)(inB + (size_t)n * 65536) : nullptr;

    if (INM == 1 && tid < 64) sb[tid] = bias2[tid];
    for (int i = tid; i < 144; i += 256) {
        int ci = i / 18, row = i % 18;
        lin[ci][row][0] = 0.f;
        lin[ci][row][33] = 0.f;
    }

    float acc[8][2];
    #pragma unroll
    for (int co = 0; co < 8; ++co) { acc[co][0] = acc[co][1] = 0.f; }

    for (int cic = 0; cic < 8; ++cic) {
        __syncthreads();
        for (int i = tid; i < 1152; i += 256) {
            int ci = i / 144, rr = i % 144;
            int row = rr >> 3, q = rr & 7;
            int gy = h * 16 - 1 + row;
            float4 v = make_float4(0.f, 0.f, 0.f, 0.f);
            if (gy >= 0 && gy < 32) {
                int idx = (cic * 8 + ci) * 256 + gy * 8 + q;
                v = inA4[idx];
                if (INM == 1) {
                    float4 vb = inB4[idx];
                    float bb = sb[cic * 8 + ci];
                    v.x = lrelu(v.x + vb.x + bb);
                    v.y = lrelu(v.y + vb.y + bb);
                    v.z = lrelu(v.z + vb.z + bb);
                    v.w = lrelu(v.w + vb.w + bb);
                }
            }
            float* dst = &lin[ci][row][1 + 4 * q];
            dst[0] = v.x; dst[1] = v.y; dst[2] = v.z; dst[3] = v.w;
        }
        for (int i = tid; i < 576; i += 256) {
            int ci = i / 72, rr = i % 72;
            int co = rr / 9, tt = rr % 9;
            lw[ci][co][tt] = w[((cg * 8 + co) * 64 + cic * 8 + ci) * 9 + tt];
        }
        __syncthreads();
        #pragma unroll 2
        for (int ci = 0; ci < 8; ++ci) {
            float win[3][4];
            #pragma unroll
            for (int dy = 0; dy < 3; ++dy)
                #pragma unroll
                for (int dx = 0; dx < 4; ++dx)
                    win[dy][dx] = lin[ci][r + dy][c0 + dx];
            #pragma unroll
            for (int co = 0; co < 8; ++co) {
                #pragma unroll
                for (int dy = 0; dy < 3; ++dy)
                    #pragma unroll
                    for (int dx = 0; dx < 3; ++dx) {
                        float wvv = lw[ci][co][dy * 3 + dx];
                        acc[co][0] = fmaf(win[dy][dx],     wvv, acc[co][0]);
                        acc[co][1] = fmaf(win[dy][dx + 1], wvv, acc[co][1]);
                    }
            }
        }
    }
    size_t ob = ((size_t)(n * 64 + cg * 8) << 10) + (h * 16 + r) * 32 + c0;
    #pragma unroll
    for (int co = 0; co < 8; ++co) {
        float bv = bias ? bias[cg * 8 + co] : 0.f;
        float a0 = acc[co][0] + bv, a1 = acc[co][1] + bv;
        if (ACT == 1) { a0 = lrelu(a0); a1 = lrelu(a1); }
        float2 v; v.x = a0; v.y = a1;
        *(float2*)(out + ob + ((size_t)co << 10)) = v;
        if (STATS) {
            float s = a0 + a1;
            float q = a0 * a0 + a1 * a1;
            #pragma unroll
            for (int m = 1; m < 64; m <<= 1) {
                s += __shfl_xor(s, m);
                q += __shfl_xor(q, m);
            }
            if (lane == 0) { sS[co][wv_id] = s; sQ[co][wv_id] = q; }
        }
    }
    if (STATS) {
        __syncthreads();
        if (tid < 8) {
            float s = sS[tid][0] + sS[tid][1] + sS[tid][2] + sS[tid][3];
            float q = sQ[tid][0] + sQ[tid][1] + sQ[tid][2] + sQ[tid][3];
            psum[(cg * 8 + tid) * 128 + n * 2 + h] = s;
            pss [(cg * 8 + tid) * 128 + n * 2 + h] = q;
        }
    }
}

// ================= conv1x1 fp32 (encoder), fused BN input / stats =================
template<int IN, int ACT, int STATS>
__global__ void __launch_bounds__(256) conv1x1_t(
    const float* __restrict__ in, const float* __restrict__ res,
    const float* __restrict__ w, const float* __restrict__ bias,
    const float* __restrict__ fin, const float* __restrict__ g,
    const float* __restrict__ beta, float* __restrict__ out,
    float* __restrict__ psum, float* __restrict__ pss)
{
    __shared__ float lw[64][8];
    __shared__ float sga[64], sbb[64];
    __shared__ float sS[8][4], sQ[8][4];
    int b = blockIdx.x;
    int n = b & 63, cg = b >> 6;
    int tid = threadIdx.x;
    int lane = tid & 63, wv_id = tid >> 6;
    for (int i = tid; i < 512; i += 256) {
        int ci = i >> 3, co = i & 7;
        lw[ci][co] = w[(cg * 8 + co) * 64 + ci];
    }
    if (IN >= 1 && tid < 64) {
        float ga = g[tid] * fin[2 * tid + 1];
        sga[tid] = ga;
        sbb[tid] = beta[tid] - fin[2 * tid] * ga;
    }
    __syncthreads();
    const float4* in4 = (const float4*)(in + (size_t)n * 65536);
    const float4* res4 = (IN == 2) ? (const float4*)(res + (size_t)n * 65536) : nullptr;
    float acc[8][4];
    #pragma unroll
    for (int co = 0; co < 8; ++co) { acc[co][0]=acc[co][1]=acc[co][2]=acc[co][3]=0.f; }
    #pragma unroll 4
    for (int ci = 0; ci < 64; ++ci) {
        float4 xv = in4[(ci << 8) + tid];
        float x0, x1, x2, x3;
        if (IN == 1) {
            float ga = sga[ci], bb = sbb[ci];
            x0 = fmaxf(fmaf(xv.x, ga, bb), 0.f);
            x1 = fmaxf(fmaf(xv.y, ga, bb), 0.f);
            x2 = fmaxf(fmaf(xv.z, ga, bb), 0.f);
            x3 = fmaxf(fmaf(xv.w, ga, bb), 0.f);
        } else if (IN == 2) {
            float4 rv = res4[(ci << 8) + tid];
            float ga = sga[ci], bb = sbb[ci];
            x0 = lrelu(rv.x + fmaf(xv.x, ga, bb));
            x1 = lrelu(rv.y + fmaf(xv.y, ga, bb));
            x2 = lrelu(rv.z + fmaf(xv.z, ga, bb));
            x3 = lrelu(rv.w + fmaf(xv.w, ga, bb));
        } else {
            x0 = xv.x; x1 = xv.y; x2 = xv.z; x3 = xv.w;
        }
        #pragma unroll
        for (int co = 0; co < 8; ++co) {
            float wvv = lw[ci][co];
            acc[co][0] = fmaf(x0, wvv, acc[co][0]);
            acc[co][1] = fmaf(x1, wvv, acc[co][1]);
            acc[co][2] = fmaf(x2, wvv, acc[co][2]);
            acc[co][3] = fmaf(x3, wvv, acc[co][3]);
        }
    }
    #pragma unroll
    for (int co = 0; co < 8; ++co) {
        float bv = bias ? bias[cg * 8 + co] : 0.f;
        float a0 = acc[co][0] + bv, a1 = acc[co][1] + bv, a2 = acc[co][2] + bv, a3 = acc[co][3] + bv;
        if (ACT == 1) { a0 = lrelu(a0); a1 = lrelu(a1); a2 = lrelu(a2); a3 = lrelu(a3); }
        float4 v; v.x = a0; v.y = a1; v.z = a2; v.w = a3;
        ((float4*)(out + (size_t)n * 65536 + (size_t)(cg * 8 + co) * 1024))[tid] = v;
        if (STATS) {
            float s = a0 + a1 + a2 + a3;
            float q = a0*a0 + a1*a1 + a2*a2 + a3*a3;
            #pragma unroll
            for (int m = 1; m < 64; m <<= 1) {
                s += __shfl_xor(s, m);
                q += __shfl_xor(q, m);
            }
            if (lane == 0) { sS[co][wv_id] = s; sQ[co][wv_id] = q; }
        }
    }
    if (STATS) {
        __syncthreads();
        if (tid < 8) {
            float s = sS[tid][0] + sS[tid][1] + sS[tid][2] + sS[tid][3];
            float q = sQ[tid][0] + sQ[tid][1] + sQ[tid][2] + sQ[tid][3];
            psum[(cg * 8 + tid) * 64 + n] = s;
            pss [(cg * 8 + tid) * 64 + n] = q;
        }
    }
}

// ================= BN finalize from per-(c, slice) partials =================
__global__ void bn_fin2_k(const float* __restrict__ psum, const float* __restrict__ pss,
                          float* __restrict__ fin, float invM, int cnt)
{
    int c = threadIdx.x;
    if (c >= 64) return;
    float s = 0.f, q = 0.f;
    for (int i = 0; i < cnt; ++i) { s += psum[c * cnt + i]; q += pss[c * cnt + i]; }
    float mean = s * invM;
    float var  = q * invM - mean * mean;
    fin[2 * c] = mean;
    fin[2 * c + 1] = rsqrtf(var + 1e-5f);
}

// ================= BN finalize (decoder MFMA partials: [c][256]) =================
__global__ void bn_fin3_k(const float* __restrict__ psum, const float* __restrict__ pss,
                          float* __restrict__ fin, float invM)
{
    int c = threadIdx.x;
    if (c >= 64) return;
    float s = 0.f, q = 0.f;
    for (int i = 0; i < 256; ++i) { s += psum[c * 256 + i]; q += pss[c * 256 + i]; }
    float mean = s * invM;
    float var  = q * invM - mean * mean;
    fin[2 * c] = mean;
    fin[2 * c + 1] = rsqrtf(var + 1e-5f);
}

// ================= transpose NCHW fp32 -> NHWC bf16 (+optional BN-relu) =================
template<int MODE>
__global__ void __launch_bounds__(256) trans_k(
    const float* __restrict__ in, const float* __restrict__ fin,
    const float* __restrict__ g, const float* __restrict__ beta,
    unsigned short* __restrict__ outT)
{
    __shared__ unsigned short tt[256][68];
    __shared__ float sga[64], sbb[64];
    int b = blockIdx.x;
    int n = b >> 2, pxb = b & 3;
    int tid = threadIdx.x;
    if (MODE == 1) {
        if (tid < 64) {
            float ga = g[tid] * fin[2 * tid + 1];
            sga[tid] = ga;
            sbb[tid] = beta[tid] - fin[2 * tid] * ga;
        }
        __syncthreads();
    }
    for (int i = tid; i < 16384; i += 256) {
        int ci = i >> 8, px = i & 255;
        float v = in[((size_t)(n * 64 + ci) << 10) + pxb * 256 + px];
        if (MODE == 1) v = fmaxf(fmaf(v, sga[ci], sbb[ci]), 0.f);
        tt[px][ci] = f2bf(v);
    }
    __syncthreads();
    for (int o = tid; o < 4096; o += 256) {
        int px = o >> 4, c4 = o & 15;
        uint2 v = *(const uint2*)&tt[px][c4 * 4];
        *(uint2*)(outT + ((((size_t)n << 10) + pxb * 256 + px) << 6) + c4 * 4) = v;
    }
}

// ================= fused lrelu(res + bn(x)) + NCHW fp32 -> NHWC bf16 =================
__global__ void __launch_bounds__(256) bnres_trans_k(
    const float* __restrict__ xin, const float* __restrict__ res,
    const float* __restrict__ fin, const float* __restrict__ g,
    const float* __restrict__ beta, unsigned short* __restrict__ outT)
{
    __shared__ unsigned short tt[256][68];
    __shared__ float sga[64], sbb[64];
    int b = blockIdx.x;
    int n = b >> 2, pxb = b & 3;
    int tid = threadIdx.x;
    if (tid < 64) {
        float ga = g[tid] * fin[2 * tid + 1];
        sga[tid] = ga;
        sbb[tid] = beta[tid] - fin[2 * tid] * ga;
    }
    __syncthreads();
    for (int i = tid; i < 16384; i += 256) {
        int ci = i >> 8, px = i & 255;
        size_t gi = ((size_t)(n * 64 + ci) << 10) + pxb * 256 + px;
        float v = lrelu(res[gi] + fmaf(xin[gi], sga[ci], sbb[ci]));
        tt[px][ci] = f2bf(v);
    }
    __syncthreads();
    for (int o = tid; o < 4096; o += 256) {
        int px = o >> 4, c4 = o & 15;
        uint2 v = *(const uint2*)&tt[px][c4 * 4];
        *(uint2*)(outT + ((((size_t)n << 10) + pxb * 256 + px) << 6) + c4 * 4) = v;
    }
}

// ================= MFMA conv3x3 64->64 @32x32, bf16 (decoder) =================
template<int ACT, int STATS>
__global__ void __launch_bounds__(256) mfma_conv3x3_k(
    const unsigned short* __restrict__ inT, const float* __restrict__ w,
    const float* __restrict__ bias, float* __restrict__ out,
    float* __restrict__ psum, float* __restrict__ pss)
{
    __shared__ unsigned short lin[10][34][40];
    __shared__ unsigned short lwA[32][296];
    __shared__ float sS[4][32], sQ[4][32];
    int b = blockIdx.x;
    int cg = b & 1, pxb = (b >> 1) & 3, n = b >> 3;
    int tid = threadIdx.x;
    int wv = tid >> 6, l = tid & 63;
    int l15 = l & 15, lhi = l >> 4;

    f32x4 acc[2][4];
    #pragma unroll
    for (int ct = 0; ct < 2; ++ct)
        #pragma unroll
        for (int bt = 0; bt < 4; ++bt) {
            f32x4 z = {0.f, 0.f, 0.f, 0.f};
            acc[ct][bt] = z;
        }

    for (int c2 = 0; c2 < 2; ++c2) {
        __syncthreads();
        for (int i = tid; i < 1360; i += 256) {
            int pos = i >> 2, q = i & 3;
            int row = pos / 34, col = pos % 34;
            int iy = pxb * 8 - 1 + row, ix = col - 1;
            uint4 v = make_uint4(0u, 0u, 0u, 0u);
            if (iy >= 0 && iy < 32 && ix >= 0 && ix < 32)
                v = *(const uint4*)(inT + ((((size_t)n << 10) + iy * 32 + ix) << 6) + c2 * 32 + q * 8);
            *(uint4*)&lin[row][col][q * 8] = v;
        }
        for (int i = tid; i < 9216; i += 256) {
            int col = i / 288, k = i % 288;
            int tap = k >> 5, cc = k & 31;
            int co = cg * 32 + col;
            lwA[col][k] = f2bf(w[(co * 64 + c2 * 32 + cc) * 9 + tap]);
        }
        __syncthreads();
        #pragma unroll
        for (int tap = 0; tap < 9; ++tap) {
            const int dy = tap / 3, dx = tap % 3;
            short8 a[2], bb[4];
            #pragma unroll
            for (int ct = 0; ct < 2; ++ct)
                a[ct] = *(const short8*)&lwA[ct * 16 + l15][tap * 32 + lhi * 8];
            #pragma unroll
            for (int bt = 0; bt < 4; ++bt) {
                int rr = 2 * wv + (bt >> 1);
                int cc0 = (bt & 1) * 16;
                bb[bt] = *(const short8*)&lin[rr + dy][cc0 + l15 + dx][lhi * 8];
            }
            #pragma unroll
            for (int ct = 0; ct < 2; ++ct)
                #pragma unroll
                for (int bt = 0; bt < 4; ++bt)
                    acc[ct][bt] = __builtin_amdgcn_mfma_f32_16x16x32_bf16(a[ct], bb[bt], acc[ct][bt], 0, 0, 0);
        }
    }

    int orow0 = pxb * 8 + 2 * wv;
    #pragma unroll
    for (int ct = 0; ct < 2; ++ct) {
        #pragma unroll
        for (int j = 0; j < 4; ++j) {
            int co_l = ct * 16 + lhi * 4 + j;
            int co = cg * 32 + co_l;
            float bv = bias ? bias[co] : 0.f;
            float s = 0.f, q = 0.f;
            #pragma unroll
            for (int bt = 0; bt < 4; ++bt) {
                float v = acc[ct][bt][j] + bv;
                if (ACT == 1) v = lrelu(v);
                int row = orow0 + (bt >> 1);
                int col = (bt & 1) * 16 + l15;
                out[(((size_t)n * 64 + co) << 10) + row * 32 + col] = v;
                if (STATS) { s += v; q = fmaf(v, v, q); }
            }
            if (STATS) {
                #pragma unroll
                for (int m = 1; m < 16; m <<= 1) {
                    s += __shfl_xor(s, m);
                    q += __shfl_xor(q, m);
                }
                if (l15 == 0) { sS[wv][co_l] = s; sQ[wv][co_l] = q; }
            }
        }
    }
    if (STATS) {
        __syncthreads();
        if (tid < 32) {
            float s = sS[0][tid] + sS[1][tid] + sS[2][tid] + sS[3][tid];
            float q = sQ[0][tid] + sQ[1][tid] + sQ[2][tid] + sQ[3][tid];
            psum[(cg * 32 + tid) * 256 + n * 4 + pxb] = s;
            pss [(cg * 32 + tid) * 256 + n * 4 + pxb] = q;
        }
    }
}

// ================= MFMA conv1x1 64->64 @32x32, bf16 (decoder) =================
template<int ACT, int STATS>
__global__ void __launch_bounds__(256) mfma_conv1x1_k(
    const unsigned short* __restrict__ inT, const float* __restrict__ w,
    const float* __restrict__ bias, float* __restrict__ out,
    float* __restrict__ psum, float* __restrict__ pss)
{
    __shared__ unsigned short lin[256][72];
    __shared__ unsigned short lwA[32][72];
    __shared__ float sS[4][32], sQ[4][32];
    int b = blockIdx.x;
    int cg = b & 1, pxb = (b >> 1) & 3, n = b >> 3;
    int tid = threadIdx.x;
    int wv = tid >> 6, l = tid & 63;
    int l15 = l & 15, lhi = l >> 4;

    for (int i = tid; i < 2048; i += 256) {
        int px = i >> 3, q = i & 7;
        uint4 v = *(const uint4*)(inT + ((((size_t)n << 10) + pxb * 256 + px) << 6) + q * 8);
        *(uint4*)&lin[px][q * 8] = v;
    }
    for (int i = tid; i < 2048; i += 256) {
        int col = i >> 6, ci = i & 63;
        lwA[col][ci] = f2bf(w[(cg * 32 + col) * 64 + ci]);
    }
    __syncthreads();

    f32x4 acc[2][4];
    #pragma unroll
    for (int ct = 0; ct < 2; ++ct)
        #pragma unroll
        for (int bt = 0; bt < 4; ++bt) {
            f32x4 z = {0.f, 0.f, 0.f, 0.f};
            acc[ct][bt] = z;
        }

    #pragma unroll
    for (int ks = 0; ks < 2; ++ks) {
        short8 a[2], bb[4];
        #pragma unroll
        for (int ct = 0; ct < 2; ++ct)
            a[ct] = *(const short8*)&lwA[ct * 16 + l15][ks * 32 + lhi * 8];
        #pragma unroll
        for (int bt = 0; bt < 4; ++bt)
            bb[bt] = *(const short8*)&lin[wv * 64 + bt * 16 + l15][ks * 32 + lhi * 8];
        #pragma unroll
        for (int ct = 0; ct < 2; ++ct)
            #pragma unroll
            for (int bt = 0; bt < 4; ++bt)
                acc[ct][bt] = __builtin_amdgcn_mfma_f32_16x16x32_bf16(a[ct], bb[bt], acc[ct][bt], 0, 0, 0);
    }

    #pragma unroll
    for (int ct = 0; ct < 2; ++ct) {
        #pragma unroll
        for (int j = 0; j < 4; ++j) {
            int co_l = ct * 16 + lhi * 4 + j;
            int co = cg * 32 + co_l;
            float bv = bias ? bias[co] : 0.f;
            float s = 0.f, q = 0.f;
            #pragma unroll
            for (int bt = 0; bt < 4; ++bt) {
                float v = acc[ct][bt][j] + bv;
                if (ACT == 1) v = lrelu(v);
                int px = pxb * 256 + wv * 64 + bt * 16 + l15;
                out[(((size_t)n * 64 + co) << 10) + px] = v;
                if (STATS) { s += v; q = fmaf(v, v, q); }
            }
            if (STATS) {
                #pragma unroll
                for (int m = 1; m < 16; m <<= 1) {
                    s += __shfl_xor(s, m);
                    q += __shfl_xor(q, m);
                }
                if (l15 == 0) { sS[wv][co_l] = s; sQ[wv][co_l] = q; }
            }
        }
    }
    if (STATS) {
        __syncthreads();
        if (tid < 32) {
            float s = sS[0][tid] + sS[1][tid] + sS[2][tid] + sS[3][tid];
            float q = sQ[0][tid] + sQ[1][tid] + sQ[2][tid] + sQ[3][tid];
            psum[(cg * 32 + tid) * 256 + n * 4 + pxb] = s;
            pss [(cg * 32 + tid) * 256 + n * 4 + pxb] = q;
        }
    }
}

// ================= MFMA dt1: deconv 64->32, 32x32 -> 64x64, lrelu (bf16) =================
__global__ void __launch_bounds__(256) mfma_dt1_k(
    const unsigned short* __restrict__ inT, const float* __restrict__ w,
    const float* __restrict__ bias, float* __restrict__ out)
{
    __shared__ unsigned short lin[5][34][40];
    __shared__ unsigned short lwA[2][32][136];
    int b = blockIdx.x;
    int ublk = b & 7, p_y = (b >> 3) & 1, n = b >> 4;
    int tid = threadIdx.x;
    int wv = tid >> 6, l = tid & 63;
    int l15 = l & 15, lhi = l >> 4;
    int pq = wv & 1;
    int vbase = 1 - pq;
    int ubase = ublk * 4 + (p_y == 0 ? 1 : 0);

    f32x4 acc[2][4];
    #pragma unroll
    for (int ct = 0; ct < 2; ++ct)
        #pragma unroll
        for (int bt = 0; bt < 4; ++bt) {
            f32x4 z = {0.f, 0.f, 0.f, 0.f};
            acc[ct][bt] = z;
        }

    for (int ch = 0; ch < 2; ++ch) {
        __syncthreads();
        for (int i = tid; i < 680; i += 256) {
            int rr = i / 136, rem = i % 136;
            int jc = rem >> 2, q = rem & 3;
            int gy = ubase - 1 + rr, gx = jc - 1;
            uint4 v = make_uint4(0u, 0u, 0u, 0u);
            if (gy >= 0 && gy < 32 && gx >= 0 && gx < 32)
                v = *(const uint4*)(inT + ((((size_t)n << 10) + gy * 32 + gx) << 6) + ch * 32 + q * 8);
            *(uint4*)&lin[rr][jc][q * 8] = v;
        }
        for (int i = tid; i < 8192; i += 256) {
            int pqq = i >> 12, co = (i >> 7) & 31, k = i & 127;
            int tap = k >> 5, cc = k & 31;
            int ci = ch * 32 + cc;
            int ky = p_y + 2 * (tap >> 1), kx = pqq + 2 * (tap & 1);
            lwA[pqq][co][k] = f2bf(w[((ci * 32 + co) << 4) + ky * 4 + kx]);
        }
        __syncthreads();
        #pragma unroll
        for (int ks = 0; ks < 4; ++ks) {
            int ty = ks >> 1, tx = ks & 1;
            short8 a[2], bb[4];
            #pragma unroll
            for (int ct = 0; ct < 2; ++ct)
                a[ct] = *(const short8*)&lwA[pq][ct * 16 + l15][ks * 32 + lhi * 8];
            #pragma unroll
            for (int bt = 0; bt < 4; ++bt) {
                int jloc = (wv >> 1) * 2 + (bt >> 1);
                int vloc = (bt & 1) * 16 + l15;
                bb[bt] = *(const short8*)&lin[jloc + 1 - ty][vloc + vbase + 1 - tx][lhi * 8];
            }
            #pragma unroll
            for (int ct = 0; ct < 2; ++ct)
                #pragma unroll
                for (int bt = 0; bt < 4; ++bt)
                    acc[ct][bt] = __builtin_amdgcn_mfma_f32_16x16x32_bf16(a[ct], bb[bt], acc[ct][bt], 0, 0, 0);
        }
    }

    #pragma unroll
    for (int ct = 0; ct < 2; ++ct) {
        #pragma unroll
        for (int j = 0; j < 4; ++j) {
            int co = ct * 16 + lhi * 4 + j;
            float bv = bias[co];
            #pragma unroll
            for (int bt = 0; bt < 4; ++bt) {
                int jloc = (wv >> 1) * 2 + (bt >> 1);
                int vloc = (bt & 1) * 16 + l15;
                int oy = 2 * (ubase + jloc) - 1 + p_y;
                int ox = 2 * (vloc + vbase) - 1 + pq;
                out[((size_t)(n * 32 + co) << 12) + oy * 64 + ox] = lrelu(acc[ct][bt][j] + bv);
            }
        }
    }
}

// ================= VQ =================
__global__ void __launch_bounds__(256) vq_enorm_k(const float* __restrict__ emb, float* __restrict__ enorm)
{
    int k = blockIdx.x * 256 + threadIdx.x;
    if (k >= 512) return;
    const float4* e4 = (const float4*)(emb + (k << 6));
    float s = 0.f;
    #pragma unroll
    for (int j = 0; j < 16; ++j) {
        float4 e = e4[j];
        s = fmaf(e.x, e.x, s); s = fmaf(e.y, e.y, s);
        s = fmaf(e.z, e.z, s); s = fmaf(e.w, e.w, s);
    }
    enorm[k] = s;
}

__device__ __forceinline__ unsigned order_u32(float s) {
    unsigned u = __float_as_uint(s);
    return (s < 0.f) ? ~u : (u | 0x80000000u);
}

__global__ void __launch_bounds__(256) vq_dist_k(
    const float* __restrict__ z, const float* __restrict__ emb,
    const float* __restrict__ enorm, unsigned long long* __restrict__ best)
{
    __shared__ float se[64][64];
    __shared__ float sn[64];
    int b = blockIdx.x;
    int kb = b & 7, pg = b >> 3;
    int tid = threadIdx.x;
    for (int i = tid; i < 4096; i += 256)
        ((float*)se)[i] = emb[(kb << 12) + i];
    if (tid < 64) sn[tid] = enorm[(kb << 6) + tid];
    __syncthreads();

    int n = pg >> 1;
    int p0 = ((pg & 1) << 9) + tid;
    size_t base0 = (size_t)n * 65536 + p0;
    float z0[64], z1[64];
    #pragma unroll
    for (int d = 0; d < 64; ++d) z0[d] = z[base0 + (size_t)d * 1024];
    #pragma unroll
    for (int d = 0; d < 64; ++d) z1[d] = z[base0 + 256 + (size_t)d * 1024];

    unsigned long long b0 = ~0ULL, b1 = ~0ULL;
    for (int k = 0; k < 64; ++k) {
        const float4* e4 = (const float4*)se[k];
        float dot0 = 0.f, dot1 = 0.f;
        #pragma unroll
        for (int j = 0; j < 16; ++j) {
            float4 e = e4[j];
            dot0 = fmaf(z0[4*j],   e.x, dot0);
            dot0 = fmaf(z0[4*j+1], e.y, dot0);
            dot0 = fmaf(z0[4*j+2], e.z, dot0);
            dot0 = fmaf(z0[4*j+3], e.w, dot0);
            dot1 = fmaf(z1[4*j],   e.x, dot1);
            dot1 = fmaf(z1[4*j+1], e.y, dot1);
            dot1 = fmaf(z1[4*j+2], e.z, dot1);
            dot1 = fmaf(z1[4*j+3], e.w, dot1);
        }
        float s0 = fmaf(-2.f, dot0, sn[k]);
        float s1 = fmaf(-2.f, dot1, sn[k]);
        unsigned kk = (unsigned)((kb << 6) + k);
        unsigned long long p0k = ((unsigned long long)order_u32(s0) << 32) | kk;
        unsigned long long p1k = ((unsigned long long)order_u32(s1) << 32) | kk;
        b0 = p0k < b0 ? p0k : b0;
        b1 = p1k < b1 ? p1k : b1;
    }
    size_t m0 = ((size_t)pg << 9) + tid;
    best[((size_t)kb << 16) + m0]       = b0;
    best[((size_t)kb << 16) + m0 + 256] = b1;
}

__global__ void __launch_bounds__(256) vq_combine_k(
    const float* __restrict__ z, const float* __restrict__ emb,
    const unsigned long long* __restrict__ best,
    float* __restrict__ out_q, float* __restrict__ partials)
{
    int m = blockIdx.x * 256 + threadIdx.x;
    unsigned long long bb = best[m];
    #pragma unroll
    for (int kb = 1; kb < 8; ++kb) {
        unsigned long long v = best[((size_t)kb << 16) + m];
        bb = v < bb ? v : bb;
    }
    int bi = (int)(bb & 0x1ffu);
    int n = m >> 10, p = m & 1023;
    size_t base = (size_t)n * 65536 + p;
    const float* eb = emb + (bi << 6);
    float lsum = 0.f;
    #pragma unroll
    for (int d = 0; d < 64; ++d) {
        float zz = z[base + (size_t)d * 1024];
        float q = eb[d];
        out_q[base + (size_t)d * 1024] = q;
        float df = q - zz;
        lsum = fmaf(df, df, lsum);
    }
    __shared__ float sh[256];
    sh[threadIdx.x] = lsum;
    __syncthreads();
    for (int st = 128; st > 0; st >>= 1) {
        if (threadIdx.x < st) sh[threadIdx.x] += sh[threadIdx.x + st];
        __syncthreads();
    }
    if (threadIdx.x == 0) partials[blockIdx.x] = sh[0];
}

__global__ void vq_fin_k(const float* __restrict__ partials, float* __restrict__ out)
{
    __shared__ float sh[256];
    sh[threadIdx.x] = partials[threadIdx.x];
    __syncthreads();
    for (int st = 128; st > 0; st >>= 1) {
        if (threadIdx.x < st) sh[threadIdx.x] += sh[threadIdx.x + st];
        __syncthreads();
    }
    if (threadIdx.x == 0) out[0] = sh[0] * (0.25f / (65536.f * 64.f));
}

// ================= dt2: deconv 32->3, 64x64 -> 128x128, tanh (fp32) =================
// grid 2048: n = b&63, rt = b>>6 (32 tiles of 4 rows). thread: r4 = tid>>6, g = tid&63 (2 px)
__global__ void __launch_bounds__(256) deconv_dt2_t(
    const float* __restrict__ in, const float* __restrict__ w,
    const float* __restrict__ bias, float* __restrict__ out)
{
    __shared__ float lin[8][4][67];
    __shared__ float lw[8][3][16];
    int b = blockIdx.x;
    int n = b & 63, rt = b >> 6;
    int tid = threadIdx.x;
    int r4 = tid >> 6, g = tid & 63;
    int oy = rt * 4 + r4;
    const float* inp = in + (size_t)n * 32 * 4096;
    int iy0 = 2 * rt - 1;
    int ky0 = (oy + 1) & 1;
    int iyA = ((oy + 1 - ky0) >> 1) - iy0;
    int iyB = iyA - 1;

    float acc[3][2];
    #pragma unroll
    for (int co = 0; co < 3; ++co) { acc[co][0] = acc[co][1] = 0.f; }

    for (int cic = 0; cic < 4; ++cic) {
        __syncthreads();
        for (int i = tid; i < 2112; i += 256) {
            int ci = i / 264, rr = i % 264;
            int y = rr / 66, xx = rr % 66;
            int gy = iy0 + y, gx = xx - 1;
            float v = 0.f;
            if (gy >= 0 && gy < 64 && gx >= 0 && gx < 64)
                v = inp[(cic * 8 + ci) * 4096 + gy * 64 + gx];
            lin[ci][y][xx] = v;
        }
        for (int i = tid; i < 384; i += 256) {
            int ci = i / 48, rr = i % 48;
            int co = rr >> 4, tt = rr & 15;
            lw[ci][co][tt] = w[((cic * 8 + ci) * 3 + co) * 16 + tt];
        }
        __syncthreads();
        #pragma unroll 2
        for (int ci = 0; ci < 8; ++ci) {
            float vA0 = lin[ci][iyA][g],     vA1 = lin[ci][iyA][g + 1], vA2 = lin[ci][iyA][g + 2];
            float vB0 = lin[ci][iyB][g],     vB1 = lin[ci][iyB][g + 1], vB2 = lin[ci][iyB][g + 2];
            #pragma unroll
            for (int co = 0; co < 3; ++co) {
                const float4* wp = (const float4*)lw[ci][co];
                float4 wA = wp[ky0];
                float4 wB = wp[ky0 + 2];
                acc[co][0] = fmaf(vA1, wA.y, fmaf(vA0, wA.w, fmaf(vB1, wB.y, fmaf(vB0, wB.w, acc[co][0]))));
                acc[co][1] = fmaf(vA2, wA.x, fmaf(vA1, wA.z, fmaf(vB2, wB.x, fmaf(vB1, wB.z, acc[co][1]))));
            }
        }
    }
    #pragma unroll
    for (int co = 0; co < 3; ++co) {
        float bv = bias[co];
        float2 v;
        v.x = fast_tanh(acc[co][0] + bv);
        v.y = fast_tanh(acc[co][1] + bv);
        *(float2*)(out + ((size_t)(n * 3 + co) * 16384) + oy * 128 + 2 * g) = v;
    }
}

extern "C" void kernel_launch(void* const* d_in, const int* in_sizes, int n_in,
                              void* d_out, int out_size, void* d_ws, size_t ws_size,
                              hipStream_t stream)
{
    const float* x    = (const float*)d_in[0];
    const float* e1w  = (const float*)d_in[1];
    const float* e1b  = (const float*)d_in[2];
    const float* e2w  = (const float*)d_in[3];
    const float* e2b  = (const float*)d_in[4];
    const float* e3w  = (const float*)d_in[5];
    const float* e3b  = (const float*)d_in[6];
    const float* er1w = (const float*)d_in[7];
    const float* er1g = (const float*)d_in[8];
    const float* er1b = (const float*)d_in[9];
    const float* er2w = (const float*)d_in[10];
    const float* er2g = (const float*)d_in[11];
    const float* er2b = (const float*)d_in[12];
    const float* e4w  = (const float*)d_in[13];
    const float* e4b  = (const float*)d_in[14];
    const float* emb  = (const float*)d_in[15];
    const float* d1w  = (const float*)d_in[16];
    const float* d1b  = (const float*)d_in[17];
    const float* dr1w = (const float*)d_in[18];
    const float* dr1g = (const float*)d_in[19];
    const float* dr1b = (const float*)d_in[20];
    const float* dr2w = (const float*)d_in[21];
    const float* dr2g = (const float*)d_in[22];
    const float* dr2b = (const float*)d_in[23];
    const float* dt1w = (const float*)d_in[24];
    const float* dt1b = (const float*)d_in[25];
    const float* dt2w = (const float*)d_in[26];
    const float* dt2b = (const float*)d_in[27];

    float* out = (float*)d_out;
    float* ws  = (float*)d_ws;

    // workspace layout (floats)
    float* B0 = ws;                   // 8,388,608
    float* B1 = ws + 8388608;         // 4,194,304
    float* B2 = B1 + 4194304;
    float* B3 = B2 + 4194304;
    float* B4 = B3 + 4194304;
    float* psum   = B4 + 4194304;     // 16384
    float* pss    = psum + 16384;     // 16384
    float* fin    = pss + 16384;      // 128
    float* vq_part = fin + 128;       // 256
    float* enorm   = vq_part + 256;   // 512
    unsigned long long* bestbuf = (unsigned long long*)(enorm + 512);  // 4MB

    unsigned short* tbuf = (unsigned short*)B1;  // 8.4MB bf16 NHWC (decoder phase)

    float* out_recon = out;                 // 3,145,728
    float* out_q     = out + 3145728;       // 4,194,304
    float* out_e     = out + 7340032;       // 4,194,304 (scratch for e2 partial until e4 overwrites)
    float* out_loss  = out + 11534336;      // 1

    const float invM = 1.f / 65536.f;

    // ---------------- encoder (fp32 — protects VQ argmin) ----------------
    conv_e1_t<<<1024, 256, 0, stream>>>(x, e1w, e1b, B0);
    // e2 as 2 ci-half partials: B1 (ci 0..15) + out_e (ci 16..31); bias+lrelu applied in e3 staging
    conv_e2p_k<<<1024, 256, 0, stream>>>(B0, e2w, B1, out_e);
    conv3x3_t<1,1,0><<<1024, 256, 0, stream>>>(B1, out_e, e2b, e3w, e3b, B2, nullptr, nullptr);

    conv3x3_t<0,0,1><<<1024, 256, 0, stream>>>(B2, nullptr, nullptr, er1w, nullptr, B3, psum, pss);
    bn_fin2_k<<<1, 64, 0, stream>>>(psum, pss, fin, invM, 128);
    conv1x1_t<1,0,1><<<512, 256, 0, stream>>>(B3, nullptr, er2w, nullptr, fin, er1g, er1b, B4, psum, pss);
    bn_fin2_k<<<1, 64, 0, stream>>>(psum, pss, fin, invM, 64);
    conv1x1_t<2,1,0><<<512, 256, 0, stream>>>(B4, B2, e4w, e4b, fin, er2g, er2b, out_e, nullptr, nullptr);

    // VQ (fp32)
    vq_enorm_k<<<2, 256, 0, stream>>>(emb, enorm);
    vq_dist_k<<<1024, 256, 0, stream>>>(out_e, emb, enorm, bestbuf);
    vq_combine_k<<<256, 256, 0, stream>>>(out_e, emb, bestbuf, out_q, vq_part);
    vq_fin_k<<<1, 256, 0, stream>>>(vq_part, out_loss);

    // ---------------- decoder (bf16 MFMA) ----------------
    trans_k<0><<<256, 256, 0, stream>>>(out_q, nullptr, nullptr, nullptr, tbuf);
    mfma_conv3x3_k<1,0><<<512, 256, 0, stream>>>(tbuf, d1w, d1b, B2, nullptr, nullptr);

    trans_k<0><<<256, 256, 0, stream>>>(B2, nullptr, nullptr, nullptr, tbuf);
    mfma_conv3x3_k<0,1><<<512, 256, 0, stream>>>(tbuf, dr1w, nullptr, B3, psum, pss);
    bn_fin3_k<<<1, 64, 0, stream>>>(psum, pss, fin, invM);

    trans_k<1><<<256, 256, 0, stream>>>(B3, fin, dr1g, dr1b, tbuf);
    mfma_conv1x1_k<0,1><<<512, 256, 0, stream>>>(tbuf, dr2w, nullptr, B4, psum, pss);
    bn_fin3_k<<<1, 64, 0, stream>>>(psum, pss, fin, invM);

    bnres_trans_k<<<256, 256, 0, stream>>>(B4, B2, fin, dr2g, dr2b, tbuf);
    mfma_dt1_k<<<1024, 256, 0, stream>>>(tbuf, dt1w, dt1b, B0);

    deconv_dt2_t<<<2048, 256, 0, stream>>>(B0, dt2w, dt2b, out_recon);
}

// Round 11
// 620.891 us; speedup vs baseline: 1.0494x; 1.0494x over previous
//
#include <hip/hip_runtime.h>
#include <math.h>

#define LREL 0.01f
__device__ __forceinline__ float lrelu(float x) { return x > 0.f ? x : LREL * x; }
__device__ __forceinline__ float fast_tanh(float x) {
    x = fminf(fmaxf(x, -10.f), 10.f);
    float a = __expf(2.f * x);
    return (a - 1.f) / (a + 1.f);
}
__device__ __forceinline__ unsigned short f2bf(float f) {
    unsigned u = __float_as_uint(f);
    unsigned r = u + 0x7FFFu + ((u >> 16) & 1u);
    return (unsigned short)(r >> 16);
}

typedef __attribute__((ext_vector_type(8))) short short8;
typedef __attribute__((ext_vector_type(4))) float f32x4;

// ================= e1: 3->32, 128x128 -> 64x64, 4x4 s2 p1, lrelu (fp32) =================
// grid 1024: n = b&63 ; t = b>>6: rt = t&7 (8 row tiles of 8), cg = t>>3 (2 groups of 16 co)
__global__ void __launch_bounds__(256) conv_e1_t(
    const float* __restrict__ x, const float* __restrict__ w,
    const float* __restrict__ bias, float* __restrict__ out)
{
    __shared__ float lin[3][18][131];
    __shared__ float lw[3][16][16];
    int b = blockIdx.x;
    int n = b & 63, t = b >> 6;
    int rt = t & 7, cg = t >> 3;
    int tid = threadIdx.x;
    int r = tid >> 5, g = tid & 31;
    const float* inp = x + (size_t)n * 3 * 16384;

    for (int i = tid; i < 7020; i += 256) {
        int ci = i / 2340, rr = i % 2340;
        int row = rr / 130, xx = rr % 130;
        int gy = 16 * rt - 1 + row, gx = xx - 1;
        float v = 0.f;
        if (gy >= 0 && gy < 128 && gx >= 0 && gx < 128)
            v = inp[ci * 16384 + gy * 128 + gx];
        lin[ci][row][xx] = v;
    }
    for (int i = tid; i < 768; i += 256) {
        int ci = i >> 8, rr = i & 255, co = rr >> 4, tt = rr & 15;
        lw[ci][co][tt] = w[((cg * 16 + co) * 3 + ci) * 16 + tt];
    }
    __syncthreads();

    float acc[16][2];
    #pragma unroll
    for (int co = 0; co < 16; ++co) { acc[co][0] = acc[co][1] = 0.f; }

    #pragma unroll
    for (int ci = 0; ci < 3; ++ci) {
        float win[4][6];
        #pragma unroll
        for (int ky = 0; ky < 4; ++ky)
            #pragma unroll
            for (int dx = 0; dx < 6; ++dx)
                win[ky][dx] = lin[ci][2 * r + ky][4 * g + dx];
        #pragma unroll
        for (int co = 0; co < 16; ++co) {
            #pragma unroll
            for (int ky = 0; ky < 4; ++ky)
                #pragma unroll
                for (int kx = 0; kx < 4; ++kx) {
                    float wv = lw[ci][co][ky * 4 + kx];
                    acc[co][0] = fmaf(win[ky][kx],     wv, acc[co][0]);
                    acc[co][1] = fmaf(win[ky][kx + 2], wv, acc[co][1]);
                }
        }
    }
    int oy = 8 * rt + r;
    #pragma unroll
    for (int co = 0; co < 16; ++co) {
        float bv = bias[cg * 16 + co];
        float2 v;
        v.x = lrelu(acc[co][0] + bv);
        v.y = lrelu(acc[co][1] + bv);
        *(float2*)(out + ((size_t)(n * 32 + cg * 16 + co) << 12) + oy * 64 + 2 * g) = v;
    }
}

// ================= e2 partial: 32->64, 64x64 -> 32x32, 16-ci halves, no bias/act =================
// grid 1024: n = b&63, ry = (b>>6)&7 (4-row tiles), ch = b>>9 (ci half)
__global__ void __launch_bounds__(256) conv_e2p_k(
    const float* __restrict__ in, const float* __restrict__ w,
    float* __restrict__ outA, float* __restrict__ outB)
{
    __shared__ float lin[4][10][66];
    __shared__ float lw[4][64][16];
    int b = blockIdx.x;
    int n = b & 63, ry = (b >> 6) & 7, ch = b >> 9;
    int tid = threadIdx.x;
    int c = tid & 31, cog = tid >> 5;
    int iy0 = 8 * ry - 1;
    const float* inp = in + (size_t)n * 32 * 4096;
    float* outp = (ch ? outB : outA);

    float acc[8][4];
    #pragma unroll
    for (int q = 0; q < 8; ++q) { acc[q][0]=acc[q][1]=acc[q][2]=acc[q][3]=0.f; }

    for (int cic = 0; cic < 4; ++cic) {
        __syncthreads();
        for (int i = tid; i < 2640; i += 256) {
            int ci = i / 660, rr = i % 660;
            int riy = rr / 66, j = rr % 66;
            int gy = iy0 + riy, gx = j - 1;
            float v = 0.f;
            if (gy >= 0 && gy < 64 && gx >= 0 && gx < 64)
                v = inp[(ch * 16 + cic * 4 + ci) * 4096 + gy * 64 + gx];
            lin[ci][riy][j] = v;
        }
        for (int i = tid; i < 4096; i += 256) {
            int ci = i >> 10, rr = i & 1023, co = rr >> 4, tt = rr & 15;
            lw[ci][co][tt] = w[(co * 32 + ch * 16 + cic * 4 + ci) * 16 + tt];
        }
        __syncthreads();
        #pragma unroll
        for (int ci = 0; ci < 4; ++ci) {
            float win[10][4];
            #pragma unroll
            for (int riy = 0; riy < 10; ++riy)
                #pragma unroll
                for (int q = 0; q < 4; ++q)
                    win[riy][q] = lin[ci][riy][2 * c + q];
            #pragma unroll
            for (int cq = 0; cq < 8; ++cq) {
                const float* wp = lw[ci][cog * 8 + cq];
                #pragma unroll
                for (int r = 0; r < 4; ++r)
                    #pragma unroll
                    for (int ky = 0; ky < 4; ++ky)
                        #pragma unroll
                        for (int kx = 0; kx < 4; ++kx)
                            acc[cq][r] = fmaf(win[2 * r + ky][kx], wp[ky * 4 + kx], acc[cq][r]);
            }
        }
    }
    #pragma unroll
    for (int cq = 0; cq < 8; ++cq) {
        int co = cog * 8 + cq;
        #pragma unroll
        for (int r = 0; r < 4; ++r)
            outp[((size_t)(n * 64 + co) << 10) + (4 * ry + r) * 32 + c] = acc[cq][r];
    }
}

// ================= conv3x3 fp32 (encoder), R9 fat-thread geometry =================
// grid 512: n = b&63 ; cg = b>>6. INM: 0 plain, 1 lrelu(A+B+bias2). ACT: 0 none, 1 lrelu.
template<int INM, int ACT, int STATS>
__global__ void __launch_bounds__(256) conv3x3_t(
    const float* __restrict__ inA, const float* __restrict__ inB,
    const float* __restrict__ bias2, const float* __restrict__ w,
    const float* __restrict__ bias, float* __restrict__ out,
    float* __restrict__ psum, float* __restrict__ pss)
{
    __shared__ float lin[8][34][35];
    __shared__ float lw[8][8][9];
    __shared__ float sb[64];
    __shared__ float sS[8][4], sQ[8][4];
    int b = blockIdx.x;
    int n = b & 63, cg = b >> 6;
    int tid = threadIdx.x;
    int r = tid >> 3, g = tid & 7, c0 = g << 2;
    int lane = tid & 63, wv_id = tid >> 6;
    const float4* inA4 = (const float4*)(inA + (size_t)n * 65536);
    const float4* inB4 = (INM == 1) ? (const float4*)(inB + (size_t)n * 65536) : nullptr;

    if (INM == 1 && tid < 64) sb[tid] = bias2[tid];

    float acc[8][4];
    #pragma unroll
    for (int co = 0; co < 8; ++co) { acc[co][0]=acc[co][1]=acc[co][2]=acc[co][3]=0.f; }

    for (int i = tid; i < 8 * 34 * 35; i += 256) ((float*)lin)[i] = 0.f;

    for (int cic = 0; cic < 8; ++cic) {
        __syncthreads();
        for (int i = tid; i < 2048; i += 256) {
            int ci = i >> 8, p = i & 255;
            int row = p >> 3, qq = p & 7;
            float4 v = inA4[(cic * 8 + ci) * 256 + p];
            if (INM == 1) {
                float4 vb = inB4[(cic * 8 + ci) * 256 + p];
                float bb = sb[cic * 8 + ci];
                v.x = lrelu(v.x + vb.x + bb);
                v.y = lrelu(v.y + vb.y + bb);
                v.z = lrelu(v.z + vb.z + bb);
                v.w = lrelu(v.w + vb.w + bb);
            }
            float* dst = &lin[ci][row + 1][1 + 4 * qq];
            dst[0] = v.x; dst[1] = v.y; dst[2] = v.z; dst[3] = v.w;
        }
        for (int i = tid; i < 576; i += 256) {
            int ci = i / 72, rr = i % 72;
            int co = rr / 9, tt = rr % 9;
            lw[ci][co][tt] = w[((cg * 8 + co) * 64 + cic * 8 + ci) * 9 + tt];
        }
        __syncthreads();
        #pragma unroll 2
        for (int ci = 0; ci < 8; ++ci) {
            float win[3][6];
            #pragma unroll
            for (int dy = 0; dy < 3; ++dy)
                #pragma unroll
                for (int dx = 0; dx < 6; ++dx)
                    win[dy][dx] = lin[ci][r + dy][c0 + dx];
            #pragma unroll
            for (int co = 0; co < 8; ++co) {
                #pragma unroll
                for (int dy = 0; dy < 3; ++dy)
                    #pragma unroll
                    for (int dx = 0; dx < 3; ++dx) {
                        float wvv = lw[ci][co][dy * 3 + dx];
                        #pragma unroll
                        for (int j = 0; j < 4; ++j)
                            acc[co][j] = fmaf(win[dy][j + dx], wvv, acc[co][j]);
                    }
            }
        }
    }
    size_t ob = ((size_t)(n * 64 + cg * 8) << 10) + (r << 5) + c0;
    #pragma unroll
    for (int co = 0; co < 8; ++co) {
        float bv = bias ? bias[cg * 8 + co] : 0.f;
        float a0 = acc[co][0] + bv, a1 = acc[co][1] + bv, a2 = acc[co][2] + bv, a3 = acc[co][3] + bv;
        if (ACT == 1) { a0 = lrelu(a0); a1 = lrelu(a1); a2 = lrelu(a2); a3 = lrelu(a3); }
        float4 v; v.x = a0; v.y = a1; v.z = a2; v.w = a3;
        *(float4*)(out + ob + ((size_t)co << 10)) = v;
        if (STATS) {
            float s = a0 + a1 + a2 + a3;
            float q = a0*a0 + a1*a1 + a2*a2 + a3*a3;
            #pragma unroll
            for (int m = 1; m < 64; m <<= 1) {
                s += __shfl_xor(s, m);
                q += __shfl_xor(q, m);
            }
            if (lane == 0) { sS[co][wv_id] = s; sQ[co][wv_id] = q; }
        }
    }
    if (STATS) {
        __syncthreads();
        if (tid < 8) {
            float s = sS[tid][0] + sS[tid][1] + sS[tid][2] + sS[tid][3];
            float q = sQ[tid][0] + sQ[tid][1] + sQ[tid][2] + sQ[tid][3];
            psum[(cg * 8 + tid) * 64 + n] = s;
            pss [(cg * 8 + tid) * 64 + n] = q;
        }
    }
}

// ================= conv1x1 fp32 (encoder), fused BN input / stats =================
template<int IN, int ACT, int STATS>
__global__ void __launch_bounds__(256) conv1x1_t(
    const float* __restrict__ in, const float* __restrict__ res,
    const float* __restrict__ w, const float* __restrict__ bias,
    const float* __restrict__ fin, const float* __restrict__ g,
    const float* __restrict__ beta, float* __restrict__ out,
    float* __restrict__ psum, float* __restrict__ pss)
{
    __shared__ float lw[64][8];
    __shared__ float sga[64], sbb[64];
    __shared__ float sS[8][4], sQ[8][4];
    int b = blockIdx.x;
    int n = b & 63, cg = b >> 6;
    int tid = threadIdx.x;
    int lane = tid & 63, wv_id = tid >> 6;
    for (int i = tid; i < 512; i += 256) {
        int ci = i >> 3, co = i & 7;
        lw[ci][co] = w[(cg * 8 + co) * 64 + ci];
    }
    if (IN >= 1 && tid < 64) {
        float ga = g[tid] * fin[2 * tid + 1];
        sga[tid] = ga;
        sbb[tid] = beta[tid] - fin[2 * tid] * ga;
    }
    __syncthreads();
    const float4* in4 = (const float4*)(in + (size_t)n * 65536);
    const float4* res4 = (IN == 2) ? (const float4*)(res + (size_t)n * 65536) : nullptr;
    float acc[8][4];
    #pragma unroll
    for (int co = 0; co < 8; ++co) { acc[co][0]=acc[co][1]=acc[co][2]=acc[co][3]=0.f; }
    #pragma unroll 4
    for (int ci = 0; ci < 64; ++ci) {
        float4 xv = in4[(ci << 8) + tid];
        float x0, x1, x2, x3;
        if (IN == 1) {
            float ga = sga[ci], bb = sbb[ci];
            x0 = fmaxf(fmaf(xv.x, ga, bb), 0.f);
            x1 = fmaxf(fmaf(xv.y, ga, bb), 0.f);
            x2 = fmaxf(fmaf(xv.z, ga, bb), 0.f);
            x3 = fmaxf(fmaf(xv.w, ga, bb), 0.f);
        } else if (IN == 2) {
            float4 rv = res4[(ci << 8) + tid];
            float ga = sga[ci], bb = sbb[ci];
            x0 = lrelu(rv.x + fmaf(xv.x, ga, bb));
            x1 = lrelu(rv.y + fmaf(xv.y, ga, bb));
            x2 = lrelu(rv.z + fmaf(xv.z, ga, bb));
            x3 = lrelu(rv.w + fmaf(xv.w, ga, bb));
        } else {
            x0 = xv.x; x1 = xv.y; x2 = xv.z; x3 = xv.w;
        }
        #pragma unroll
        for (int co = 0; co < 8; ++co) {
            float wvv = lw[ci][co];
            acc[co][0] = fmaf(x0, wvv, acc[co][0]);
            acc[co][1] = fmaf(x1, wvv, acc[co][1]);
            acc[co][2] = fmaf(x2, wvv, acc[co][2]);
            acc[co][3] = fmaf(x3, wvv, acc[co][3]);
        }
    }
    #pragma unroll
    for (int co = 0; co < 8; ++co) {
        float bv = bias ? bias[cg * 8 + co] : 0.f;
        float a0 = acc[co][0] + bv, a1 = acc[co][1] + bv, a2 = acc[co][2] + bv, a3 = acc[co][3] + bv;
        if (ACT == 1) { a0 = lrelu(a0); a1 = lrelu(a1); a2 = lrelu(a2); a3 = lrelu(a3); }
        float4 v; v.x = a0; v.y = a1; v.z = a2; v.w = a3;
        ((float4*)(out + (size_t)n * 65536 + (size_t)(cg * 8 + co) * 1024))[tid] = v;
        if (STATS) {
            float s = a0 + a1 + a2 + a3;
            float q = a0*a0 + a1*a1 + a2*a2 + a3*a3;
            #pragma unroll
            for (int m = 1; m < 64; m <<= 1) {
                s += __shfl_xor(s, m);
                q += __shfl_xor(q, m);
            }
            if (lane == 0) { sS[co][wv_id] = s; sQ[co][wv_id] = q; }
        }
    }
    if (STATS) {
        __syncthreads();
        if (tid < 8) {
            float s = sS[tid][0] + sS[tid][1] + sS[tid][2] + sS[tid][3];
            float q = sQ[tid][0] + sQ[tid][1] + sQ[tid][2] + sQ[tid][3];
            psum[(cg * 8 + tid) * 64 + n] = s;
            pss [(cg * 8 + tid) * 64 + n] = q;
        }
    }
}

// ================= BN finalize from per-(c, slice) partials =================
__global__ void bn_fin2_k(const float* __restrict__ psum, const float* __restrict__ pss,
                          float* __restrict__ fin, float invM, int cnt)
{
    int c = threadIdx.x;
    if (c >= 64) return;
    float s = 0.f, q = 0.f;
    for (int i = 0; i < cnt; ++i) { s += psum[c * cnt + i]; q += pss[c * cnt + i]; }
    float mean = s * invM;
    float var  = q * invM - mean * mean;
    fin[2 * c] = mean;
    fin[2 * c + 1] = rsqrtf(var + 1e-5f);
}

// ================= BN finalize (decoder MFMA partials: [c][256]) =================
__global__ void bn_fin3_k(const float* __restrict__ psum, const float* __restrict__ pss,
                          float* __restrict__ fin, float invM)
{
    int c = threadIdx.x;
    if (c >= 64) return;
    float s = 0.f, q = 0.f;
    for (int i = 0; i < 256; ++i) { s += psum[c * 256 + i]; q += pss[c * 256 + i]; }
    float mean = s * invM;
    float var  = q * invM - mean * mean;
    fin[2 * c] = mean;
    fin[2 * c + 1] = rsqrtf(var + 1e-5f);
}

// ================= transpose NCHW fp32 -> NHWC bf16 (+optional BN-relu) =================
template<int MODE>
__global__ void __launch_bounds__(256) trans_k(
    const float* __restrict__ in, const float* __restrict__ fin,
    const float* __restrict__ g, const float* __restrict__ beta,
    unsigned short* __restrict__ outT)
{
    __shared__ unsigned short tt[256][68];
    __shared__ float sga[64], sbb[64];
    int b = blockIdx.x;
    int n = b >> 2, pxb = b & 3;
    int tid = threadIdx.x;
    if (MODE == 1) {
        if (tid < 64) {
            float ga = g[tid] * fin[2 * tid + 1];
            sga[tid] = ga;
            sbb[tid] = beta[tid] - fin[2 * tid] * ga;
        }
        __syncthreads();
    }
    for (int i = tid; i < 16384; i += 256) {
        int ci = i >> 8, px = i & 255;
        float v = in[((size_t)(n * 64 + ci) << 10) + pxb * 256 + px];
        if (MODE == 1) v = fmaxf(fmaf(v, sga[ci], sbb[ci]), 0.f);
        tt[px][ci] = f2bf(v);
    }
    __syncthreads();
    for (int o = tid; o < 4096; o += 256) {
        int px = o >> 4, c4 = o & 15;
        uint2 v = *(const uint2*)&tt[px][c4 * 4];
        *(uint2*)(outT + ((((size_t)n << 10) + pxb * 256 + px) << 6) + c4 * 4) = v;
    }
}

// ================= fused lrelu(res + bn(x)) + NCHW fp32 -> NHWC bf16 =================
__global__ void __launch_bounds__(256) bnres_trans_k(
    const float* __restrict__ xin, const float* __restrict__ res,
    const float* __restrict__ fin, const float* __restrict__ g,
    const float* __restrict__ beta, unsigned short* __restrict__ outT)
{
    __shared__ unsigned short tt[256][68];
    __shared__ float sga[64], sbb[64];
    int b = blockIdx.x;
    int n = b >> 2, pxb = b & 3;
    int tid = threadIdx.x;
    if (tid < 64) {
        float ga = g[tid] * fin[2 * tid + 1];
        sga[tid] = ga;
        sbb[tid] = beta[tid] - fin[2 * tid] * ga;
    }
    __syncthreads();
    for (int i = tid; i < 16384; i += 256) {
        int ci = i >> 8, px = i & 255;
        size_t gi = ((size_t)(n * 64 + ci) << 10) + pxb * 256 + px;
        float v = lrelu(res[gi] + fmaf(xin[gi], sga[ci], sbb[ci]));
        tt[px][ci] = f2bf(v);
    }
    __syncthreads();
    for (int o = tid; o < 4096; o += 256) {
        int px = o >> 4, c4 = o & 15;
        uint2 v = *(const uint2*)&tt[px][c4 * 4];
        *(uint2*)(outT + ((((size_t)n << 10) + pxb * 256 + px) << 6) + c4 * 4) = v;
    }
}

// ================= MFMA conv3x3 64->64 @32x32, bf16 (decoder) =================
template<int ACT, int STATS>
__global__ void __launch_bounds__(256) mfma_conv3x3_k(
    const unsigned short* __restrict__ inT, const float* __restrict__ w,
    const float* __restrict__ bias, float* __restrict__ out,
    float* __restrict__ psum, float* __restrict__ pss)
{
    __shared__ unsigned short lin[10][34][40];
    __shared__ unsigned short lwA[32][296];
    __shared__ float sS[4][32], sQ[4][32];
    int b = blockIdx.x;
    int cg = b & 1, pxb = (b >> 1) & 3, n = b >> 3;
    int tid = threadIdx.x;
    int wv = tid >> 6, l = tid & 63;
    int l15 = l & 15, lhi = l >> 4;

    f32x4 acc[2][4];
    #pragma unroll
    for (int ct = 0; ct < 2; ++ct)
        #pragma unroll
        for (int bt = 0; bt < 4; ++bt) {
            f32x4 z = {0.f, 0.f, 0.f, 0.f};
            acc[ct][bt] = z;
        }

    for (int c2 = 0; c2 < 2; ++c2) {
        __syncthreads();
        for (int i = tid; i < 1360; i += 256) {
            int pos = i >> 2, q = i & 3;
            int row = pos / 34, col = pos % 34;
            int iy = pxb * 8 - 1 + row, ix = col - 1;
            uint4 v = make_uint4(0u, 0u, 0u, 0u);
            if (iy >= 0 && iy < 32 && ix >= 0 && ix < 32)
                v = *(const uint4*)(inT + ((((size_t)n << 10) + iy * 32 + ix) << 6) + c2 * 32 + q * 8);
            *(uint4*)&lin[row][col][q * 8] = v;
        }
        for (int i = tid; i < 9216; i += 256) {
            int col = i / 288, k = i % 288;
            int tap = k >> 5, cc = k & 31;
            int co = cg * 32 + col;
            lwA[col][k] = f2bf(w[(co * 64 + c2 * 32 + cc) * 9 + tap]);
        }
        __syncthreads();
        #pragma unroll
        for (int tap = 0; tap < 9; ++tap) {
            const int dy = tap / 3, dx = tap % 3;
            short8 a[2], bb[4];
            #pragma unroll
            for (int ct = 0; ct < 2; ++ct)
                a[ct] = *(const short8*)&lwA[ct * 16 + l15][tap * 32 + lhi * 8];
            #pragma unroll
            for (int bt = 0; bt < 4; ++bt) {
                int rr = 2 * wv + (bt >> 1);
                int cc0 = (bt & 1) * 16;
                bb[bt] = *(const short8*)&lin[rr + dy][cc0 + l15 + dx][lhi * 8];
            }
            #pragma unroll
            for (int ct = 0; ct < 2; ++ct)
                #pragma unroll
                for (int bt = 0; bt < 4; ++bt)
                    acc[ct][bt] = __builtin_amdgcn_mfma_f32_16x16x32_bf16(a[ct], bb[bt], acc[ct][bt], 0, 0, 0);
        }
    }

    int orow0 = pxb * 8 + 2 * wv;
    #pragma unroll
    for (int ct = 0; ct < 2; ++ct) {
        #pragma unroll
        for (int j = 0; j < 4; ++j) {
            int co_l = ct * 16 + lhi * 4 + j;
            int co = cg * 32 + co_l;
            float bv = bias ? bias[co] : 0.f;
            float s = 0.f, q = 0.f;
            #pragma unroll
            for (int bt = 0; bt < 4; ++bt) {
                float v = acc[ct][bt][j] + bv;
                if (ACT == 1) v = lrelu(v);
                int row = orow0 + (bt >> 1);
                int col = (bt & 1) * 16 + l15;
                out[(((size_t)n * 64 + co) << 10) + row * 32 + col] = v;
                if (STATS) { s += v; q = fmaf(v, v, q); }
            }
            if (STATS) {
                #pragma unroll
                for (int m = 1; m < 16; m <<= 1) {
                    s += __shfl_xor(s, m);
                    q += __shfl_xor(q, m);
                }
                if (l15 == 0) { sS[wv][co_l] = s; sQ[wv][co_l] = q; }
            }
        }
    }
    if (STATS) {
        __syncthreads();
        if (tid < 32) {
            float s = sS[0][tid] + sS[1][tid] + sS[2][tid] + sS[3][tid];
            float q = sQ[0][tid] + sQ[1][tid] + sQ[2][tid] + sQ[3][tid];
            psum[(cg * 32 + tid) * 256 + n * 4 + pxb] = s;
            pss [(cg * 32 + tid) * 256 + n * 4 + pxb] = q;
        }
    }
}

// ================= MFMA conv1x1 64->64 @32x32, bf16 (decoder) =================
template<int ACT, int STATS>
__global__ void __launch_bounds__(256) mfma_conv1x1_k(
    const unsigned short* __restrict__ inT, const float* __restrict__ w,
    const float* __restrict__ bias, float* __restrict__ out,
    float* __restrict__ psum, float* __restrict__ pss)
{
    __shared__ unsigned short lin[256][72];
    __shared__ unsigned short lwA[32][72];
    __shared__ float sS[4][32], sQ[4][32];
    int b = blockIdx.x;
    int cg = b & 1, pxb = (b >> 1) & 3, n = b >> 3;
    int tid = threadIdx.x;
    int wv = tid >> 6, l = tid & 63;
    int l15 = l & 15, lhi = l >> 4;

    for (int i = tid; i < 2048; i += 256) {
        int px = i >> 3, q = i & 7;
        uint4 v = *(const uint4*)(inT + ((((size_t)n << 10) + pxb * 256 + px) << 6) + q * 8);
        *(uint4*)&lin[px][q * 8] = v;
    }
    for (int i = tid; i < 2048; i += 256) {
        int col = i >> 6, ci = i & 63;
        lwA[col][ci] = f2bf(w[(cg * 32 + col) * 64 + ci]);
    }
    __syncthreads();

    f32x4 acc[2][4];
    #pragma unroll
    for (int ct = 0; ct < 2; ++ct)
        #pragma unroll
        for (int bt = 0; bt < 4; ++bt) {
            f32x4 z = {0.f, 0.f, 0.f, 0.f};
            acc[ct][bt] = z;
        }

    #pragma unroll
    for (int ks = 0; ks < 2; ++ks) {
        short8 a[2], bb[4];
        #pragma unroll
        for (int ct = 0; ct < 2; ++ct)
            a[ct] = *(const short8*)&lwA[ct * 16 + l15][ks * 32 + lhi * 8];
        #pragma unroll
        for (int bt = 0; bt < 4; ++bt)
            bb[bt] = *(const short8*)&lin[wv * 64 + bt * 16 + l15][ks * 32 + lhi * 8];
        #pragma unroll
        for (int ct = 0; ct < 2; ++ct)
            #pragma unroll
            for (int bt = 0; bt < 4; ++bt)
                acc[ct][bt] = __builtin_amdgcn_mfma_f32_16x16x32_bf16(a[ct], bb[bt], acc[ct][bt], 0, 0, 0);
    }

    #pragma unroll
    for (int ct = 0; ct < 2; ++ct) {
        #pragma unroll
        for (int j = 0; j < 4; ++j) {
            int co_l = ct * 16 + lhi * 4 + j;
            int co = cg * 32 + co_l;
            float bv = bias ? bias[co] : 0.f;
            float s = 0.f, q = 0.f;
            #pragma unroll
            for (int bt = 0; bt < 4; ++bt) {
                float v = acc[ct][bt][j] + bv;
                if (ACT == 1) v = lrelu(v);
                int px = pxb * 256 + wv * 64 + bt * 16 + l15;
                out[(((size_t)n * 64 + co) << 10) + px] = v;
                if (STATS) { s += v; q = fmaf(v, v, q); }
            }
            if (STATS) {
                #pragma unroll
                for (int m = 1; m < 16; m <<= 1) {
                    s += __shfl_xor(s, m);
                    q += __shfl_xor(q, m);
                }
                if (l15 == 0) { sS[wv][co_l] = s; sQ[wv][co_l] = q; }
            }
        }
    }
    if (STATS) {
        __syncthreads();
        if (tid < 32) {
            float s = sS[0][tid] + sS[1][tid] + sS[2][tid] + sS[3][tid];
            float q = sQ[0][tid] + sQ[1][tid] + sQ[2][tid] + sQ[3][tid];
            psum[(cg * 32 + tid) * 256 + n * 4 + pxb] = s;
            pss [(cg * 32 + tid) * 256 + n * 4 + pxb] = q;
        }
    }
}

// ================= MFMA dt1: deconv 64->32, 32x32 -> 64x64, lrelu (bf16) =================
__global__ void __launch_bounds__(256) mfma_dt1_k(
    const unsigned short* __restrict__ inT, const float* __restrict__ w,
    const float* __restrict__ bias, float* __restrict__ out)
{
    __shared__ unsigned short lin[5][34][40];
    __shared__ unsigned short lwA[2][32][136];
    int b = blockIdx.x;
    int ublk = b & 7, p_y = (b >> 3) & 1, n = b >> 4;
    int tid = threadIdx.x;
    int wv = tid >> 6, l = tid & 63;
    int l15 = l & 15, lhi = l >> 4;
    int pq = wv & 1;
    int vbase = 1 - pq;
    int ubase = ublk * 4 + (p_y == 0 ? 1 : 0);

    f32x4 acc[2][4];
    #pragma unroll
    for (int ct = 0; ct < 2; ++ct)
        #pragma unroll
        for (int bt = 0; bt < 4; ++bt) {
            f32x4 z = {0.f, 0.f, 0.f, 0.f};
            acc[ct][bt] = z;
        }

    for (int ch = 0; ch < 2; ++ch) {
        __syncthreads();
        for (int i = tid; i < 680; i += 256) {
            int rr = i / 136, rem = i % 136;
            int jc = rem >> 2, q = rem & 3;
            int gy = ubase - 1 + rr, gx = jc - 1;
            uint4 v = make_uint4(0u, 0u, 0u, 0u);
            if (gy >= 0 && gy < 32 && gx >= 0 && gx < 32)
                v = *(const uint4*)(inT + ((((size_t)n << 10) + gy * 32 + gx) << 6) + ch * 32 + q * 8);
            *(uint4*)&lin[rr][jc][q * 8] = v;
        }
        for (int i = tid; i < 8192; i += 256) {
            int pqq = i >> 12, co = (i >> 7) & 31, k = i & 127;
            int tap = k >> 5, cc = k & 31;
            int ci = ch * 32 + cc;
            int ky = p_y + 2 * (tap >> 1), kx = pqq + 2 * (tap & 1);
            lwA[pqq][co][k] = f2bf(w[((ci * 32 + co) << 4) + ky * 4 + kx]);
        }
        __syncthreads();
        #pragma unroll
        for (int ks = 0; ks < 4; ++ks) {
            int ty = ks >> 1, tx = ks & 1;
            short8 a[2], bb[4];
            #pragma unroll
            for (int ct = 0; ct < 2; ++ct)
                a[ct] = *(const short8*)&lwA[pq][ct * 16 + l15][ks * 32 + lhi * 8];
            #pragma unroll
            for (int bt = 0; bt < 4; ++bt) {
                int jloc = (wv >> 1) * 2 + (bt >> 1);
                int vloc = (bt & 1) * 16 + l15;
                bb[bt] = *(const short8*)&lin[jloc + 1 - ty][vloc + vbase + 1 - tx][lhi * 8];
            }
            #pragma unroll
            for (int ct = 0; ct < 2; ++ct)
                #pragma unroll
                for (int bt = 0; bt < 4; ++bt)
                    acc[ct][bt] = __builtin_amdgcn_mfma_f32_16x16x32_bf16(a[ct], bb[bt], acc[ct][bt], 0, 0, 0);
        }
    }

    #pragma unroll
    for (int ct = 0; ct < 2; ++ct) {
        #pragma unroll
        for (int j = 0; j < 4; ++j) {
            int co = ct * 16 + lhi * 4 + j;
            float bv = bias[co];
            #pragma unroll
            for (int bt = 0; bt < 4; ++bt) {
                int jloc = (wv >> 1) * 2 + (bt >> 1);
                int vloc = (bt & 1) * 16 + l15;
                int oy = 2 * (ubase + jloc) - 1 + p_y;
                int ox = 2 * (vloc + vbase) - 1 + pq;
                out[((size_t)(n * 32 + co) << 12) + oy * 64 + ox] = lrelu(acc[ct][bt][j] + bv);
            }
        }
    }
}

// ================= VQ =================
__global__ void __launch_bounds__(256) vq_enorm_k(const float* __restrict__ emb, float* __restrict__ enorm)
{
    int k = blockIdx.x * 256 + threadIdx.x;
    if (k >= 512) return;
    const float4* e4 = (const float4*)(emb + (k << 6));
    float s = 0.f;
    #pragma unroll
    for (int j = 0; j < 16; ++j) {
        float4 e = e4[j];
        s = fmaf(e.x, e.x, s); s = fmaf(e.y, e.y, s);
        s = fmaf(e.z, e.z, s); s = fmaf(e.w, e.w, s);
    }
    enorm[k] = s;
}

__device__ __forceinline__ unsigned order_u32(float s) {
    unsigned u = __float_as_uint(s);
    return (s < 0.f) ? ~u : (u | 0x80000000u);
}

__global__ void __launch_bounds__(256) vq_dist_k(
    const float* __restrict__ z, const float* __restrict__ emb,
    const float* __restrict__ enorm, unsigned long long* __restrict__ best)
{
    __shared__ float se[64][64];
    __shared__ float sn[64];
    int b = blockIdx.x;
    int kb = b & 7, pg = b >> 3;
    int tid = threadIdx.x;
    for (int i = tid; i < 4096; i += 256)
        ((float*)se)[i] = emb[(kb << 12) + i];
    if (tid < 64) sn[tid] = enorm[(kb << 6) + tid];
    __syncthreads();

    int n = pg >> 1;
    int p0 = ((pg & 1) << 9) + tid;
    size_t base0 = (size_t)n * 65536 + p0;
    float z0[64], z1[64];
    #pragma unroll
    for (int d = 0; d < 64; ++d) z0[d] = z[base0 + (size_t)d * 1024];
    #pragma unroll
    for (int d = 0; d < 64; ++d) z1[d] = z[base0 + 256 + (size_t)d * 1024];

    unsigned long long b0 = ~0ULL, b1 = ~0ULL;
    for (int k = 0; k < 64; ++k) {
        const float4* e4 = (const float4*)se[k];
        float dot0 = 0.f, dot1 = 0.f;
        #pragma unroll
        for (int j = 0; j < 16; ++j) {
            float4 e = e4[j];
            dot0 = fmaf(z0[4*j],   e.x, dot0);
            dot0 = fmaf(z0[4*j+1], e.y, dot0);
            dot0 = fmaf(z0[4*j+2], e.z, dot0);
            dot0 = fmaf(z0[4*j+3], e.w, dot0);
            dot1 = fmaf(z1[4*j],   e.x, dot1);
            dot1 = fmaf(z1[4*j+1], e.y, dot1);
            dot1 = fmaf(z1[4*j+2], e.z, dot1);
            dot1 = fmaf(z1[4*j+3], e.w, dot1);
        }
        float s0 = fmaf(-2.f, dot0, sn[k]);
        float s1 = fmaf(-2.f, dot1, sn[k]);
        unsigned kk = (unsigned)((kb << 6) + k);
        unsigned long long p0k = ((unsigned long long)order_u32(s0) << 32) | kk;
        unsigned long long p1k = ((unsigned long long)order_u32(s1) << 32) | kk;
        b0 = p0k < b0 ? p0k : b0;
        b1 = p1k < b1 ? p1k : b1;
    }
    size_t m0 = ((size_t)pg << 9) + tid;
    best[((size_t)kb << 16) + m0]       = b0;
    best[((size_t)kb << 16) + m0 + 256] = b1;
}

__global__ void __launch_bounds__(256) vq_combine_k(
    const float* __restrict__ z, const float* __restrict__ emb,
    const unsigned long long* __restrict__ best,
    float* __restrict__ out_q, float* __restrict__ partials)
{
    int m = blockIdx.x * 256 + threadIdx.x;
    unsigned long long bb = best[m];
    #pragma unroll
    for (int kb = 1; kb < 8; ++kb) {
        unsigned long long v = best[((size_t)kb << 16) + m];
        bb = v < bb ? v : bb;
    }
    int bi = (int)(bb & 0x1ffu);
    int n = m >> 10, p = m & 1023;
    size_t base = (size_t)n * 65536 + p;
    const float* eb = emb + (bi << 6);
    float lsum = 0.f;
    #pragma unroll
    for (int d = 0; d < 64; ++d) {
        float zz = z[base + (size_t)d * 1024];
        float q = eb[d];
        out_q[base + (size_t)d * 1024] = q;
        float df = q - zz;
        lsum = fmaf(df, df, lsum);
    }
    __shared__ float sh[256];
    sh[threadIdx.x] = lsum;
    __syncthreads();
    for (int st = 128; st > 0; st >>= 1) {
        if (threadIdx.x < st) sh[threadIdx.x] += sh[threadIdx.x + st];
        __syncthreads();
    }
    if (threadIdx.x == 0) partials[blockIdx.x] = sh[0];
}

__global__ void vq_fin_k(const float* __restrict__ partials, float* __restrict__ out)
{
    __shared__ float sh[256];
    sh[threadIdx.x] = partials[threadIdx.x];
    __syncthreads();
    for (int st = 128; st > 0; st >>= 1) {
        if (threadIdx.x < st) sh[threadIdx.x] += sh[threadIdx.x + st];
        __syncthreads();
    }
    if (threadIdx.x == 0) out[0] = sh[0] * (0.25f / (65536.f * 64.f));
}

// ================= dt2: deconv 32->3, 64x64 -> 128x128, tanh (fp32) =================
// grid 2048: n = b&63, rt = b>>6 (32 tiles of 4 rows). thread: r4 = tid>>6, g = tid&63 (2 px)
__global__ void __launch_bounds__(256) deconv_dt2_t(
    const float* __restrict__ in, const float* __restrict__ w,
    const float* __restrict__ bias, float* __restrict__ out)
{
    __shared__ float lin[8][4][67];
    __shared__ float lw[8][3][16];
    int b = blockIdx.x;
    int n = b & 63, rt = b >> 6;
    int tid = threadIdx.x;
    int r4 = tid >> 6, g = tid & 63;
    int oy = rt * 4 + r4;
    const float* inp = in + (size_t)n * 32 * 4096;
    int iy0 = 2 * rt - 1;
    int ky0 = (oy + 1) & 1;
    int iyA = ((oy + 1 - ky0) >> 1) - iy0;
    int iyB = iyA - 1;

    float acc[3][2];
    #pragma unroll
    for (int co = 0; co < 3; ++co) { acc[co][0] = acc[co][1] = 0.f; }

    for (int cic = 0; cic < 4; ++cic) {
        __syncthreads();
        for (int i = tid; i < 2112; i += 256) {
            int ci = i / 264, rr = i % 264;
            int y = rr / 66, xx = rr % 66;
            int gy = iy0 + y, gx = xx - 1;
            float v = 0.f;
            if (gy >= 0 && gy < 64 && gx >= 0 && gx < 64)
                v = inp[(cic * 8 + ci) * 4096 + gy * 64 + gx];
            lin[ci][y][xx] = v;
        }
        for (int i = tid; i < 384; i += 256) {
            int ci = i / 48, rr = i % 48;
            int co = rr >> 4, tt = rr & 15;
            lw[ci][co][tt] = w[((cic * 8 + ci) * 3 + co) * 16 + tt];
        }
        __syncthreads();
        #pragma unroll 2
        for (int ci = 0; ci < 8; ++ci) {
            float vA0 = lin[ci][iyA][g],     vA1 = lin[ci][iyA][g + 1], vA2 = lin[ci][iyA][g + 2];
            float vB0 = lin[ci][iyB][g],     vB1 = lin[ci][iyB][g + 1], vB2 = lin[ci][iyB][g + 2];
            #pragma unroll
            for (int co = 0; co < 3; ++co) {
                const float4* wp = (const float4*)lw[ci][co];
                float4 wA = wp[ky0];
                float4 wB = wp[ky0 + 2];
                acc[co][0] = fmaf(vA1, wA.y, fmaf(vA0, wA.w, fmaf(vB1, wB.y, fmaf(vB0, wB.w, acc[co][0]))));
                acc[co][1] = fmaf(vA2, wA.x, fmaf(vA1, wA.z, fmaf(vB2, wB.x, fmaf(vB1, wB.z, acc[co][1]))));
            }
        }
    }
    #pragma unroll
    for (int co = 0; co < 3; ++co) {
        float bv = bias[co];
        float2 v;
        v.x = fast_tanh(acc[co][0] + bv);
        v.y = fast_tanh(acc[co][1] + bv);
        *(float2*)(out + ((size_t)(n * 3 + co) * 16384) + oy * 128 + 2 * g) = v;
    }
}

extern "C" void kernel_launch(void* const* d_in, const int* in_sizes, int n_in,
                              void* d_out, int out_size, void* d_ws, size_t ws_size,
                              hipStream_t stream)
{
    const float* x    = (const float*)d_in[0];
    const float* e1w  = (const float*)d_in[1];
    const float* e1b  = (const float*)d_in[2];
    const float* e2w  = (const float*)d_in[3];
    const float* e2b  = (const float*)d_in[4];
    const float* e3w  = (const float*)d_in[5];
    const float* e3b  = (const float*)d_in[6];
    const float* er1w = (const float*)d_in[7];
    const float* er1g = (const float*)d_in[8];
    const float* er1b = (const float*)d_in[9];
    const float* er2w = (const float*)d_in[10];
    const float* er2g = (const float*)d_in[11];
    const float* er2b = (const float*)d_in[12];
    const float* e4w  = (const float*)d_in[13];
    const float* e4b  = (const float*)d_in[14];
    const float* emb  = (const float*)d_in[15];
    const float* d1w  = (const float*)d_in[16];
    const float* d1b  = (const float*)d_in[17];
    const float* dr1w = (const float*)d_in[18];
    const float* dr1g = (const float*)d_in[19];
    const float* dr1b = (const float*)d_in[20];
    const float* dr2w = (const float*)d_in[21];
    const float* dr2g = (const float*)d_in[22];
    const float* dr2b = (const float*)d_in[23];
    const float* dt1w = (const float*)d_in[24];
    const float* dt1b = (const float*)d_in[25];
    const float* dt2w = (const float*)d_in[26];
    const float* dt2b = (const float*)d_in[27];

    float* out = (float*)d_out;
    float* ws  = (float*)d_ws;

    // workspace layout (floats)
    float* B0 = ws;                   // 8,388,608
    float* B1 = ws + 8388608;         // 4,194,304
    float* B2 = B1 + 4194304;
    float* B3 = B2 + 4194304;
    float* B4 = B3 + 4194304;
    float* psum   = B4 + 4194304;     // 16384
    float* pss    = psum + 16384;     // 16384
    float* fin    = pss + 16384;      // 128
    float* vq_part = fin + 128;       // 256
    float* enorm   = vq_part + 256;   // 512
    unsigned long long* bestbuf = (unsigned long long*)(enorm + 512);  // 4MB

    unsigned short* tbuf = (unsigned short*)B1;  // 8.4MB bf16 NHWC (decoder phase)

    float* out_recon = out;                 // 3,145,728
    float* out_q     = out + 3145728;       // 4,194,304
    float* out_e     = out + 7340032;       // 4,194,304 (scratch for e2 partial until e4 overwrites)
    float* out_loss  = out + 11534336;      // 1

    const float invM = 1.f / 65536.f;

    // ---------------- encoder (fp32 — protects VQ argmin) ----------------
    conv_e1_t<<<1024, 256, 0, stream>>>(x, e1w, e1b, B0);
    // e2 as 2 ci-half partials: B1 (ci 0..15) + out_e (ci 16..31); bias+lrelu fused into e3 staging
    conv_e2p_k<<<1024, 256, 0, stream>>>(B0, e2w, B1, out_e);
    conv3x3_t<1,1,0><<<512, 256, 0, stream>>>(B1, out_e, e2b, e3w, e3b, B2, nullptr, nullptr);

    conv3x3_t<0,0,1><<<512, 256, 0, stream>>>(B2, nullptr, nullptr, er1w, nullptr, B3, psum, pss);
    bn_fin2_k<<<1, 64, 0, stream>>>(psum, pss, fin, invM, 64);
    conv1x1_t<1,0,1><<<512, 256, 0, stream>>>(B3, nullptr, er2w, nullptr, fin, er1g, er1b, B4, psum, pss);
    bn_fin2_k<<<1, 64, 0, stream>>>(psum, pss, fin, invM, 64);
    conv1x1_t<2,1,0><<<512, 256, 0, stream>>>(B4, B2, e4w, e4b, fin, er2g, er2b, out_e, nullptr, nullptr);

    // VQ (fp32)
    vq_enorm_k<<<2, 256, 0, stream>>>(emb, enorm);
    vq_dist_k<<<1024, 256, 0, stream>>>(out_e, emb, enorm, bestbuf);
    vq_combine_k<<<256, 256, 0, stream>>>(out_e, emb, bestbuf, out_q, vq_part);
    vq_fin_k<<<1, 256, 0, stream>>>(vq_part, out_loss);

    // ---------------- decoder (bf16 MFMA) ----------------
    trans_k<0><<<256, 256, 0, stream>>>(out_q, nullptr, nullptr, nullptr, tbuf);
    mfma_conv3x3_k<1,0><<<512, 256, 0, stream>>>(tbuf, d1w, d1b, B2, nullptr, nullptr);

    trans_k<0><<<256, 256, 0, stream>>>(B2, nullptr, nullptr, nullptr, tbuf);
    mfma_conv3x3_k<0,1><<<512, 256, 0, stream>>>(tbuf, dr1w, nullptr, B3, psum, pss);
    bn_fin3_k<<<1, 64, 0, stream>>>(psum, pss, fin, invM);

    trans_k<1><<<256, 256, 0, stream>>>(B3, fin, dr1g, dr1b, tbuf);
    mfma_conv1x1_k<0,1><<<512, 256, 0, stream>>>(tbuf, dr2w, nullptr, B4, psum, pss);
    bn_fin3_k<<<1, 64, 0, stream>>>(psum, pss, fin, invM);

    bnres_trans_k<<<256, 256, 0, stream>>>(B4, B2, fin, dr2g, dr2b, tbuf);
    mfma_dt1_k<<<1024, 256, 0, stream>>>(tbuf, dt1w, dt1b, B0);

    deconv_dt2_t<<<2048, 256, 0, stream>>>(B0, dt2w, dt2b, out_recon);
}

// Round 12
// 583.425 us; speedup vs baseline: 1.1168x; 1.0642x over previous
//
#include <hip/hip_runtime.h>
#include <math.h>

#define LREL 0.01f
__device__ __forceinline__ float lrelu(float x) { return x > 0.f ? x : LREL * x; }
__device__ __forceinline__ float fast_tanh(float x) {
    x = fminf(fmaxf(x, -10.f), 10.f);
    float a = __expf(2.f * x);
    return (a - 1.f) / (a + 1.f);
}
__device__ __forceinline__ unsigned short f2bf(float f) {
    unsigned u = __float_as_uint(f);
    unsigned r = u + 0x7FFFu + ((u >> 16) & 1u);
    return (unsigned short)(r >> 16);
}

typedef __attribute__((ext_vector_type(8))) short short8;
typedef __attribute__((ext_vector_type(4))) float f32x4;

// ================= e1: 3->32, 128x128 -> 64x64, 4x4 s2 p1, lrelu (fp32) =================
// grid 1024: n = b&63 ; t = b>>6: rt = t&7 (8 row tiles of 8), cg = t>>3 (2 groups of 16 co)
__global__ void __launch_bounds__(256) conv_e1_t(
    const float* __restrict__ x, const float* __restrict__ w,
    const float* __restrict__ bias, float* __restrict__ out)
{
    __shared__ float lin[3][18][131];
    __shared__ float lw[3][16][16];
    int b = blockIdx.x;
    int n = b & 63, t = b >> 6;
    int rt = t & 7, cg = t >> 3;
    int tid = threadIdx.x;
    int r = tid >> 5, g = tid & 31;
    const float* inp = x + (size_t)n * 3 * 16384;

    // edge cols (gx=-1 and gx=128) are always zero
    #pragma unroll
    for (int ci = 0; ci < 3; ++ci)
        if (tid < 36) lin[ci][tid >> 1][(tid & 1) ? 129 : 0] = 0.f;
    // main: div-free, coalesced 128-wide
    #pragma unroll
    for (int ci = 0; ci < 3; ++ci)
        #pragma unroll
        for (int k = 0; k < 9; ++k) {
            int idx = k * 256 + tid;
            int row = idx >> 7, col = idx & 127;
            int gy = 16 * rt - 1 + row;
            float v = 0.f;
            if (gy >= 0 && gy < 128)
                v = inp[ci * 16384 + gy * 128 + col];
            lin[ci][row][col + 1] = v;
        }
    for (int i = tid; i < 768; i += 256) {
        int ci = i >> 8, rr = i & 255, co = rr >> 4, tt = rr & 15;
        lw[ci][co][tt] = w[((cg * 16 + co) * 3 + ci) * 16 + tt];
    }
    __syncthreads();

    float acc[16][2];
    #pragma unroll
    for (int co = 0; co < 16; ++co) { acc[co][0] = acc[co][1] = 0.f; }

    #pragma unroll
    for (int ci = 0; ci < 3; ++ci) {
        float win[4][6];
        #pragma unroll
        for (int ky = 0; ky < 4; ++ky)
            #pragma unroll
            for (int dx = 0; dx < 6; ++dx)
                win[ky][dx] = lin[ci][2 * r + ky][4 * g + dx];
        #pragma unroll
        for (int co = 0; co < 16; ++co) {
            #pragma unroll
            for (int ky = 0; ky < 4; ++ky)
                #pragma unroll
                for (int kx = 0; kx < 4; ++kx) {
                    float wv = lw[ci][co][ky * 4 + kx];
                    acc[co][0] = fmaf(win[ky][kx],     wv, acc[co][0]);
                    acc[co][1] = fmaf(win[ky][kx + 2], wv, acc[co][1]);
                }
        }
    }
    int oy = 8 * rt + r;
    #pragma unroll
    for (int co = 0; co < 16; ++co) {
        float bv = bias[cg * 16 + co];
        float2 v;
        v.x = lrelu(acc[co][0] + bv);
        v.y = lrelu(acc[co][1] + bv);
        *(float2*)(out + ((size_t)(n * 32 + cg * 16 + co) << 12) + oy * 64 + 2 * g) = v;
    }
}

// ================= e2 partial: 32->64, 64x64 -> 32x32, 16-ci halves, no bias/act =================
// grid 1024: n = b&63, ry = (b>>6)&7 (4-row tiles), ch = b>>9 (ci half)
__global__ void __launch_bounds__(256) conv_e2p_k(
    const float* __restrict__ in, const float* __restrict__ w,
    float* __restrict__ outA, float* __restrict__ outB)
{
    __shared__ float lin[4][10][66];
    __shared__ float lw[4][64][16];
    int b = blockIdx.x;
    int n = b & 63, ry = (b >> 6) & 7, ch = b >> 9;
    int tid = threadIdx.x;
    int c = tid & 31, cog = tid >> 5;
    int iy0 = 8 * ry - 1;
    const float* inp = in + (size_t)n * 32 * 4096;
    float* outp = (ch ? outB : outA);

    // edge cols always zero (persist across chunks)
    #pragma unroll
    for (int ci = 0; ci < 4; ++ci)
        if (tid < 20) lin[ci][tid >> 1][(tid & 1) ? 65 : 0] = 0.f;

    float acc[8][4];
    #pragma unroll
    for (int q = 0; q < 8; ++q) { acc[q][0]=acc[q][1]=acc[q][2]=acc[q][3]=0.f; }

    int scol = tid & 63, srs = tid >> 6;
    for (int cic = 0; cic < 4; ++cic) {
        __syncthreads();
        // main staging: div-free, coalesced 64-wide
        #pragma unroll
        for (int k = 0; k < 3; ++k) {
            int row = k * 4 + srs;
            if (row < 10) {
                int gy = iy0 + row;
                #pragma unroll
                for (int ci = 0; ci < 4; ++ci) {
                    float v = 0.f;
                    if (gy >= 0 && gy < 64)
                        v = inp[(ch * 16 + cic * 4 + ci) * 4096 + gy * 64 + scol];
                    lin[ci][row][scol + 1] = v;
                }
            }
        }
        for (int i = tid; i < 4096; i += 256) {
            int ci = i >> 10, rr = i & 1023, co = rr >> 4, tt = rr & 15;
            lw[ci][co][tt] = w[(co * 32 + ch * 16 + cic * 4 + ci) * 16 + tt];
        }
        __syncthreads();
        #pragma unroll
        for (int ci = 0; ci < 4; ++ci) {
            float win[10][4];
            #pragma unroll
            for (int riy = 0; riy < 10; ++riy)
                #pragma unroll
                for (int q = 0; q < 4; ++q)
                    win[riy][q] = lin[ci][riy][2 * c + q];
            #pragma unroll
            for (int cq = 0; cq < 8; ++cq) {
                const float* wp = lw[ci][cog * 8 + cq];
                #pragma unroll
                for (int r = 0; r < 4; ++r)
                    #pragma unroll
                    for (int ky = 0; ky < 4; ++ky)
                        #pragma unroll
                        for (int kx = 0; kx < 4; ++kx)
                            acc[cq][r] = fmaf(win[2 * r + ky][kx], wp[ky * 4 + kx], acc[cq][r]);
            }
        }
    }
    #pragma unroll
    for (int cq = 0; cq < 8; ++cq) {
        int co = cog * 8 + cq;
        #pragma unroll
        for (int r = 0; r < 4; ++r)
            outp[((size_t)(n * 64 + co) << 10) + (4 * ry + r) * 32 + c] = acc[cq][r];
    }
}

// ================= conv3x3 fp32 (encoder), fat-thread geometry =================
// grid 512: n = b&63 ; cg = b>>6. INM: 0 plain, 1 lrelu(A+B+bias2). ACT: 0 none, 1 lrelu.
template<int INM, int ACT, int STATS>
__global__ void __launch_bounds__(256) conv3x3_t(
    const float* __restrict__ inA, const float* __restrict__ inB,
    const float* __restrict__ bias2, const float* __restrict__ w,
    const float* __restrict__ bias, float* __restrict__ out,
    float* __restrict__ psum, float* __restrict__ pss)
{
    __shared__ float lin[8][34][35];
    __shared__ float lw[8][8][9];
    __shared__ float sb[64];
    __shared__ float sS[8][4], sQ[8][4];
    int b = blockIdx.x;
    int n = b & 63, cg = b >> 6;
    int tid = threadIdx.x;
    int r = tid >> 3, g = tid & 7, c0 = g << 2;
    int lane = tid & 63, wv_id = tid >> 6;
    const float4* inA4 = (const float4*)(inA + (size_t)n * 65536);
    const float4* inB4 = (INM == 1) ? (const float4*)(inB + (size_t)n * 65536) : nullptr;

    if (INM == 1 && tid < 64) sb[tid] = bias2[tid];

    float acc[8][4];
    #pragma unroll
    for (int co = 0; co < 8; ++co) { acc[co][0]=acc[co][1]=acc[co][2]=acc[co][3]=0.f; }

    for (int i = tid; i < 8 * 34 * 35; i += 256) ((float*)lin)[i] = 0.f;

    for (int cic = 0; cic < 8; ++cic) {
        __syncthreads();
        for (int i = tid; i < 2048; i += 256) {
            int ci = i >> 8, p = i & 255;
            int row = p >> 3, qq = p & 7;
            float4 v = inA4[(cic * 8 + ci) * 256 + p];
            if (INM == 1) {
                float4 vb = inB4[(cic * 8 + ci) * 256 + p];
                float bb = sb[cic * 8 + ci];
                v.x = lrelu(v.x + vb.x + bb);
                v.y = lrelu(v.y + vb.y + bb);
                v.z = lrelu(v.z + vb.z + bb);
                v.w = lrelu(v.w + vb.w + bb);
            }
            float* dst = &lin[ci][row + 1][1 + 4 * qq];
            dst[0] = v.x; dst[1] = v.y; dst[2] = v.z; dst[3] = v.w;
        }
        for (int i = tid; i < 576; i += 256) {
            int ci = i / 72, rr = i % 72;
            int co = rr / 9, tt = rr % 9;
            lw[ci][co][tt] = w[((cg * 8 + co) * 64 + cic * 8 + ci) * 9 + tt];
        }
        __syncthreads();
        #pragma unroll 2
        for (int ci = 0; ci < 8; ++ci) {
            float win[3][6];
            #pragma unroll
            for (int dy = 0; dy < 3; ++dy)
                #pragma unroll
                for (int dx = 0; dx < 6; ++dx)
                    win[dy][dx] = lin[ci][r + dy][c0 + dx];
            #pragma unroll
            for (int co = 0; co < 8; ++co) {
                #pragma unroll
                for (int dy = 0; dy < 3; ++dy)
                    #pragma unroll
                    for (int dx = 0; dx < 3; ++dx) {
                        float wvv = lw[ci][co][dy * 3 + dx];
                        #pragma unroll
                        for (int j = 0; j < 4; ++j)
                            acc[co][j] = fmaf(win[dy][j + dx], wvv, acc[co][j]);
                    }
            }
        }
    }
    size_t ob = ((size_t)(n * 64 + cg * 8) << 10) + (r << 5) + c0;
    #pragma unroll
    for (int co = 0; co < 8; ++co) {
        float bv = bias ? bias[cg * 8 + co] : 0.f;
        float a0 = acc[co][0] + bv, a1 = acc[co][1] + bv, a2 = acc[co][2] + bv, a3 = acc[co][3] + bv;
        if (ACT == 1) { a0 = lrelu(a0); a1 = lrelu(a1); a2 = lrelu(a2); a3 = lrelu(a3); }
        float4 v; v.x = a0; v.y = a1; v.z = a2; v.w = a3;
        *(float4*)(out + ob + ((size_t)co << 10)) = v;
        if (STATS) {
            float s = a0 + a1 + a2 + a3;
            float q = a0*a0 + a1*a1 + a2*a2 + a3*a3;
            #pragma unroll
            for (int m = 1; m < 64; m <<= 1) {
                s += __shfl_xor(s, m);
                q += __shfl_xor(q, m);
            }
            if (lane == 0) { sS[co][wv_id] = s; sQ[co][wv_id] = q; }
        }
    }
    if (STATS) {
        __syncthreads();
        if (tid < 8) {
            float s = sS[tid][0] + sS[tid][1] + sS[tid][2] + sS[tid][3];
            float q = sQ[tid][0] + sQ[tid][1] + sQ[tid][2] + sQ[tid][3];
            psum[(cg * 8 + tid) * 64 + n] = s;
            pss [(cg * 8 + tid) * 64 + n] = q;
        }
    }
}

// ================= conv1x1 fp32 (encoder), fused BN input / stats =================
template<int IN, int ACT, int STATS>
__global__ void __launch_bounds__(256) conv1x1_t(
    const float* __restrict__ in, const float* __restrict__ res,
    const float* __restrict__ w, const float* __restrict__ bias,
    const float* __restrict__ fin, const float* __restrict__ g,
    const float* __restrict__ beta, float* __restrict__ out,
    float* __restrict__ psum, float* __restrict__ pss)
{
    __shared__ float lw[64][8];
    __shared__ float sga[64], sbb[64];
    __shared__ float sS[8][4], sQ[8][4];
    int b = blockIdx.x;
    int n = b & 63, cg = b >> 6;
    int tid = threadIdx.x;
    int lane = tid & 63, wv_id = tid >> 6;
    for (int i = tid; i < 512; i += 256) {
        int ci = i >> 3, co = i & 7;
        lw[ci][co] = w[(cg * 8 + co) * 64 + ci];
    }
    if (IN >= 1 && tid < 64) {
        float ga = g[tid] * fin[2 * tid + 1];
        sga[tid] = ga;
        sbb[tid] = beta[tid] - fin[2 * tid] * ga;
    }
    __syncthreads();
    const float4* in4 = (const float4*)(in + (size_t)n * 65536);
    const float4* res4 = (IN == 2) ? (const float4*)(res + (size_t)n * 65536) : nullptr;
    float acc[8][4];
    #pragma unroll
    for (int co = 0; co < 8; ++co) { acc[co][0]=acc[co][1]=acc[co][2]=acc[co][3]=0.f; }
    #pragma unroll 4
    for (int ci = 0; ci < 64; ++ci) {
        float4 xv = in4[(ci << 8) + tid];
        float x0, x1, x2, x3;
        if (IN == 1) {
            float ga = sga[ci], bb = sbb[ci];
            x0 = fmaxf(fmaf(xv.x, ga, bb), 0.f);
            x1 = fmaxf(fmaf(xv.y, ga, bb), 0.f);
            x2 = fmaxf(fmaf(xv.z, ga, bb), 0.f);
            x3 = fmaxf(fmaf(xv.w, ga, bb), 0.f);
        } else if (IN == 2) {
            float4 rv = res4[(ci << 8) + tid];
            float ga = sga[ci], bb = sbb[ci];
            x0 = lrelu(rv.x + fmaf(xv.x, ga, bb));
            x1 = lrelu(rv.y + fmaf(xv.y, ga, bb));
            x2 = lrelu(rv.z + fmaf(xv.z, ga, bb));
            x3 = lrelu(rv.w + fmaf(xv.w, ga, bb));
        } else {
            x0 = xv.x; x1 = xv.y; x2 = xv.z; x3 = xv.w;
        }
        #pragma unroll
        for (int co = 0; co < 8; ++co) {
            float wvv = lw[ci][co];
            acc[co][0] = fmaf(x0, wvv, acc[co][0]);
            acc[co][1] = fmaf(x1, wvv, acc[co][1]);
            acc[co][2] = fmaf(x2, wvv, acc[co][2]);
            acc[co][3] = fmaf(x3, wvv, acc[co][3]);
        }
    }
    #pragma unroll
    for (int co = 0; co < 8; ++co) {
        float bv = bias ? bias[cg * 8 + co] : 0.f;
        float a0 = acc[co][0] + bv, a1 = acc[co][1] + bv, a2 = acc[co][2] + bv, a3 = acc[co][3] + bv;
        if (ACT == 1) { a0 = lrelu(a0); a1 = lrelu(a1); a2 = lrelu(a2); a3 = lrelu(a3); }
        float4 v; v.x = a0; v.y = a1; v.z = a2; v.w = a3;
        ((float4*)(out + (size_t)n * 65536 + (size_t)(cg * 8 + co) * 1024))[tid] = v;
        if (STATS) {
            float s = a0 + a1 + a2 + a3;
            float q = a0*a0 + a1*a1 + a2*a2 + a3*a3;
            #pragma unroll
            for (int m = 1; m < 64; m <<= 1) {
                s += __shfl_xor(s, m);
                q += __shfl_xor(q, m);
            }
            if (lane == 0) { sS[co][wv_id] = s; sQ[co][wv_id] = q; }
        }
    }
    if (STATS) {
        __syncthreads();
        if (tid < 8) {
            float s = sS[tid][0] + sS[tid][1] + sS[tid][2] + sS[tid][3];
            float q = sQ[tid][0] + sQ[tid][1] + sQ[tid][2] + sQ[tid][3];
            psum[(cg * 8 + tid) * 64 + n] = s;
            pss [(cg * 8 + tid) * 64 + n] = q;
        }
    }
}

// ================= BN finalize from per-(c, slice) partials =================
__global__ void bn_fin2_k(const float* __restrict__ psum, const float* __restrict__ pss,
                          float* __restrict__ fin, float invM, int cnt)
{
    int c = threadIdx.x;
    if (c >= 64) return;
    float s = 0.f, q = 0.f;
    for (int i = 0; i < cnt; ++i) { s += psum[c * cnt + i]; q += pss[c * cnt + i]; }
    float mean = s * invM;
    float var  = q * invM - mean * mean;
    fin[2 * c] = mean;
    fin[2 * c + 1] = rsqrtf(var + 1e-5f);
}

// ================= BN finalize (decoder MFMA partials: [c][256]) =================
__global__ void bn_fin3_k(const float* __restrict__ psum, const float* __restrict__ pss,
                          float* __restrict__ fin, float invM)
{
    int c = threadIdx.x;
    if (c >= 64) return;
    float s = 0.f, q = 0.f;
    for (int i = 0; i < 256; ++i) { s += psum[c * 256 + i]; q += pss[c * 256 + i]; }
    float mean = s * invM;
    float var  = q * invM - mean * mean;
    fin[2 * c] = mean;
    fin[2 * c + 1] = rsqrtf(var + 1e-5f);
}

// ================= transpose NCHW fp32 -> NHWC bf16 (+optional BN-relu) =================
template<int MODE>
__global__ void __launch_bounds__(256) trans_k(
    const float* __restrict__ in, const float* __restrict__ fin,
    const float* __restrict__ g, const float* __restrict__ beta,
    unsigned short* __restrict__ outT)
{
    __shared__ unsigned short tt[256][68];
    __shared__ float sga[64], sbb[64];
    int b = blockIdx.x;
    int n = b >> 2, pxb = b & 3;
    int tid = threadIdx.x;
    if (MODE == 1) {
        if (tid < 64) {
            float ga = g[tid] * fin[2 * tid + 1];
            sga[tid] = ga;
            sbb[tid] = beta[tid] - fin[2 * tid] * ga;
        }
        __syncthreads();
    }
    for (int i = tid; i < 16384; i += 256) {
        int ci = i >> 8, px = i & 255;
        float v = in[((size_t)(n * 64 + ci) << 10) + pxb * 256 + px];
        if (MODE == 1) v = fmaxf(fmaf(v, sga[ci], sbb[ci]), 0.f);
        tt[px][ci] = f2bf(v);
    }
    __syncthreads();
    for (int o = tid; o < 4096; o += 256) {
        int px = o >> 4, c4 = o & 15;
        uint2 v = *(const uint2*)&tt[px][c4 * 4];
        *(uint2*)(outT + ((((size_t)n << 10) + pxb * 256 + px) << 6) + c4 * 4) = v;
    }
}

// ================= fused lrelu(res + bn(x)) + NCHW fp32 -> NHWC bf16 =================
__global__ void __launch_bounds__(256) bnres_trans_k(
    const float* __restrict__ xin, const float* __restrict__ res,
    const float* __restrict__ fin, const float* __restrict__ g,
    const float* __restrict__ beta, unsigned short* __restrict__ outT)
{
    __shared__ unsigned short tt[256][68];
    __shared__ float sga[64], sbb[64];
    int b = blockIdx.x;
    int n = b >> 2, pxb = b & 3;
    int tid = threadIdx.x;
    if (tid < 64) {
        float ga = g[tid] * fin[2 * tid + 1];
        sga[tid] = ga;
        sbb[tid] = beta[tid] - fin[2 * tid] * ga;
    }
    __syncthreads();
    for (int i = tid; i < 16384; i += 256) {
        int ci = i >> 8, px = i & 255;
        size_t gi = ((size_t)(n * 64 + ci) << 10) + pxb * 256 + px;
        float v = lrelu(res[gi] + fmaf(xin[gi], sga[ci], sbb[ci]));
        tt[px][ci] = f2bf(v);
    }
    __syncthreads();
    for (int o = tid; o < 4096; o += 256) {
        int px = o >> 4, c4 = o & 15;
        uint2 v = *(const uint2*)&tt[px][c4 * 4];
        *(uint2*)(outT + ((((size_t)n << 10) + pxb * 256 + px) << 6) + c4 * 4) = v;
    }
}

// ================= MFMA conv3x3 64->64 @32x32, bf16 (decoder) =================
template<int ACT, int STATS>
__global__ void __launch_bounds__(256) mfma_conv3x3_k(
    const unsigned short* __restrict__ inT, const float* __restrict__ w,
    const float* __restrict__ bias, float* __restrict__ out,
    float* __restrict__ psum, float* __restrict__ pss)
{
    __shared__ unsigned short lin[10][34][40];
    __shared__ unsigned short lwA[32][296];
    __shared__ float sS[4][32], sQ[4][32];
    int b = blockIdx.x;
    int cg = b & 1, pxb = (b >> 1) & 3, n = b >> 3;
    int tid = threadIdx.x;
    int wv = tid >> 6, l = tid & 63;
    int l15 = l & 15, lhi = l >> 4;

    f32x4 acc[2][4];
    #pragma unroll
    for (int ct = 0; ct < 2; ++ct)
        #pragma unroll
        for (int bt = 0; bt < 4; ++bt) {
            f32x4 z = {0.f, 0.f, 0.f, 0.f};
            acc[ct][bt] = z;
        }

    for (int c2 = 0; c2 < 2; ++c2) {
        __syncthreads();
        for (int i = tid; i < 1360; i += 256) {
            int pos = i >> 2, q = i & 3;
            int row = pos / 34, col = pos % 34;
            int iy = pxb * 8 - 1 + row, ix = col - 1;
            uint4 v = make_uint4(0u, 0u, 0u, 0u);
            if (iy >= 0 && iy < 32 && ix >= 0 && ix < 32)
                v = *(const uint4*)(inT + ((((size_t)n << 10) + iy * 32 + ix) << 6) + c2 * 32 + q * 8);
            *(uint4*)&lin[row][col][q * 8] = v;
        }
        for (int i = tid; i < 9216; i += 256) {
            int col = i / 288, k = i % 288;
            int tap = k >> 5, cc = k & 31;
            int co = cg * 32 + col;
            lwA[col][k] = f2bf(w[(co * 64 + c2 * 32 + cc) * 9 + tap]);
        }
        __syncthreads();
        #pragma unroll
        for (int tap = 0; tap < 9; ++tap) {
            const int dy = tap / 3, dx = tap % 3;
            short8 a[2], bb[4];
            #pragma unroll
            for (int ct = 0; ct < 2; ++ct)
                a[ct] = *(const short8*)&lwA[ct * 16 + l15][tap * 32 + lhi * 8];
            #pragma unroll
            for (int bt = 0; bt < 4; ++bt) {
                int rr = 2 * wv + (bt >> 1);
                int cc0 = (bt & 1) * 16;
                bb[bt] = *(const short8*)&lin[rr + dy][cc0 + l15 + dx][lhi * 8];
            }
            #pragma unroll
            for (int ct = 0; ct < 2; ++ct)
                #pragma unroll
                for (int bt = 0; bt < 4; ++bt)
                    acc[ct][bt] = __builtin_amdgcn_mfma_f32_16x16x32_bf16(a[ct], bb[bt], acc[ct][bt], 0, 0, 0);
        }
    }

    int orow0 = pxb * 8 + 2 * wv;
    #pragma unroll
    for (int ct = 0; ct < 2; ++ct) {
        #pragma unroll
        for (int j = 0; j < 4; ++j) {
            int co_l = ct * 16 + lhi * 4 + j;
            int co = cg * 32 + co_l;
            float bv = bias ? bias[co] : 0.f;
            float s = 0.f, q = 0.f;
            #pragma unroll
            for (int bt = 0; bt < 4; ++bt) {
                float v = acc[ct][bt][j] + bv;
                if (ACT == 1) v = lrelu(v);
                int row = orow0 + (bt >> 1);
                int col = (bt & 1) * 16 + l15;
                out[(((size_t)n * 64 + co) << 10) + row * 32 + col] = v;
                if (STATS) { s += v; q = fmaf(v, v, q); }
            }
            if (STATS) {
                #pragma unroll
                for (int m = 1; m < 16; m <<= 1) {
                    s += __shfl_xor(s, m);
                    q += __shfl_xor(q, m);
                }
                if (l15 == 0) { sS[wv][co_l] = s; sQ[wv][co_l] = q; }
            }
        }
    }
    if (STATS) {
        __syncthreads();
        if (tid < 32) {
            float s = sS[0][tid] + sS[1][tid] + sS[2][tid] + sS[3][tid];
            float q = sQ[0][tid] + sQ[1][tid] + sQ[2][tid] + sQ[3][tid];
            psum[(cg * 32 + tid) * 256 + n * 4 + pxb] = s;
            pss [(cg * 32 + tid) * 256 + n * 4 + pxb] = q;
        }
    }
}

// ================= MFMA conv1x1 64->64 @32x32, bf16 (decoder) =================
template<int ACT, int STATS>
__global__ void __launch_bounds__(256) mfma_conv1x1_k(
    const unsigned short* __restrict__ inT, const float* __restrict__ w,
    const float* __restrict__ bias, float* __restrict__ out,
    float* __restrict__ psum, float* __restrict__ pss)
{
    __shared__ unsigned short lin[256][72];
    __shared__ unsigned short lwA[32][72];
    __shared__ float sS[4][32], sQ[4][32];
    int b = blockIdx.x;
    int cg = b & 1, pxb = (b >> 1) & 3, n = b >> 3;
    int tid = threadIdx.x;
    int wv = tid >> 6, l = tid & 63;
    int l15 = l & 15, lhi = l >> 4;

    for (int i = tid; i < 2048; i += 256) {
        int px = i >> 3, q = i & 7;
        uint4 v = *(const uint4*)(inT + ((((size_t)n << 10) + pxb * 256 + px) << 6) + q * 8);
        *(uint4*)&lin[px][q * 8] = v;
    }
    for (int i = tid; i < 2048; i += 256) {
        int col = i >> 6, ci = i & 63;
        lwA[col][ci] = f2bf(w[(cg * 32 + col) * 64 + ci]);
    }
    __syncthreads();

    f32x4 acc[2][4];
    #pragma unroll
    for (int ct = 0; ct < 2; ++ct)
        #pragma unroll
        for (int bt = 0; bt < 4; ++bt) {
            f32x4 z = {0.f, 0.f, 0.f, 0.f};
            acc[ct][bt] = z;
        }

    #pragma unroll
    for (int ks = 0; ks < 2; ++ks) {
        short8 a[2], bb[4];
        #pragma unroll
        for (int ct = 0; ct < 2; ++ct)
            a[ct] = *(const short8*)&lwA[ct * 16 + l15][ks * 32 + lhi * 8];
        #pragma unroll
        for (int bt = 0; bt < 4; ++bt)
            bb[bt] = *(const short8*)&lin[wv * 64 + bt * 16 + l15][ks * 32 + lhi * 8];
        #pragma unroll
        for (int ct = 0; ct < 2; ++ct)
            #pragma unroll
            for (int bt = 0; bt < 4; ++bt)
                acc[ct][bt] = __builtin_amdgcn_mfma_f32_16x16x32_bf16(a[ct], bb[bt], acc[ct][bt], 0, 0, 0);
    }

    #pragma unroll
    for (int ct = 0; ct < 2; ++ct) {
        #pragma unroll
        for (int j = 0; j < 4; ++j) {
            int co_l = ct * 16 + lhi * 4 + j;
            int co = cg * 32 + co_l;
            float bv = bias ? bias[co] : 0.f;
            float s = 0.f, q = 0.f;
            #pragma unroll
            for (int bt = 0; bt < 4; ++bt) {
                float v = acc[ct][bt][j] + bv;
                if (ACT == 1) v = lrelu(v);
                int px = pxb * 256 + wv * 64 + bt * 16 + l15;
                out[(((size_t)n * 64 + co) << 10) + px] = v;
                if (STATS) { s += v; q = fmaf(v, v, q); }
            }
            if (STATS) {
                #pragma unroll
                for (int m = 1; m < 16; m <<= 1) {
                    s += __shfl_xor(s, m);
                    q += __shfl_xor(q, m);
                }
                if (l15 == 0) { sS[wv][co_l] = s; sQ[wv][co_l] = q; }
            }
        }
    }
    if (STATS) {
        __syncthreads();
        if (tid < 32) {
            float s = sS[0][tid] + sS[1][tid] + sS[2][tid] + sS[3][tid];
            float q = sQ[0][tid] + sQ[1][tid] + sQ[2][tid] + sQ[3][tid];
            psum[(cg * 32 + tid) * 256 + n * 4 + pxb] = s;
            pss [(cg * 32 + tid) * 256 + n * 4 + pxb] = q;
        }
    }
}

// ================= MFMA dt1: deconv 64->32, 32x32 -> 64x64, lrelu (bf16) =================
__global__ void __launch_bounds__(256) mfma_dt1_k(
    const unsigned short* __restrict__ inT, const float* __restrict__ w,
    const float* __restrict__ bias, float* __restrict__ out)
{
    __shared__ unsigned short lin[5][34][40];
    __shared__ unsigned short lwA[2][32][136];
    int b = blockIdx.x;
    int ublk = b & 7, p_y = (b >> 3) & 1, n = b >> 4;
    int tid = threadIdx.x;
    int wv = tid >> 6, l = tid & 63;
    int l15 = l & 15, lhi = l >> 4;
    int pq = wv & 1;
    int vbase = 1 - pq;
    int ubase = ublk * 4 + (p_y == 0 ? 1 : 0);

    f32x4 acc[2][4];
    #pragma unroll
    for (int ct = 0; ct < 2; ++ct)
        #pragma unroll
        for (int bt = 0; bt < 4; ++bt) {
            f32x4 z = {0.f, 0.f, 0.f, 0.f};
            acc[ct][bt] = z;
        }

    for (int ch = 0; ch < 2; ++ch) {
        __syncthreads();
        for (int i = tid; i < 680; i += 256) {
            int rr = i / 136, rem = i % 136;
            int jc = rem >> 2, q = rem & 3;
            int gy = ubase - 1 + rr, gx = jc - 1;
            uint4 v = make_uint4(0u, 0u, 0u, 0u);
            if (gy >= 0 && gy < 32 && gx >= 0 && gx < 32)
                v = *(const uint4*)(inT + ((((size_t)n << 10) + gy * 32 + gx) << 6) + ch * 32 + q * 8);
            *(uint4*)&lin[rr][jc][q * 8] = v;
        }
        for (int i = tid; i < 8192; i += 256) {
            int pqq = i >> 12, co = (i >> 7) & 31, k = i & 127;
            int tap = k >> 5, cc = k & 31;
            int ci = ch * 32 + cc;
            int ky = p_y + 2 * (tap >> 1), kx = pqq + 2 * (tap & 1);
            lwA[pqq][co][k] = f2bf(w[((ci * 32 + co) << 4) + ky * 4 + kx]);
        }
        __syncthreads();
        #pragma unroll
        for (int ks = 0; ks < 4; ++ks) {
            int ty = ks >> 1, tx = ks & 1;
            short8 a[2], bb[4];
            #pragma unroll
            for (int ct = 0; ct < 2; ++ct)
                a[ct] = *(const short8*)&lwA[pq][ct * 16 + l15][ks * 32 + lhi * 8];
            #pragma unroll
            for (int bt = 0; bt < 4; ++bt) {
                int jloc = (wv >> 1) * 2 + (bt >> 1);
                int vloc = (bt & 1) * 16 + l15;
                bb[bt] = *(const short8*)&lin[jloc + 1 - ty][vloc + vbase + 1 - tx][lhi * 8];
            }
            #pragma unroll
            for (int ct = 0; ct < 2; ++ct)
                #pragma unroll
                for (int bt = 0; bt < 4; ++bt)
                    acc[ct][bt] = __builtin_amdgcn_mfma_f32_16x16x32_bf16(a[ct], bb[bt], acc[ct][bt], 0, 0, 0);
        }
    }

    #pragma unroll
    for (int ct = 0; ct < 2; ++ct) {
        #pragma unroll
        for (int j = 0; j < 4; ++j) {
            int co = ct * 16 + lhi * 4 + j;
            float bv = bias[co];
            #pragma unroll
            for (int bt = 0; bt < 4; ++bt) {
                int jloc = (wv >> 1) * 2 + (bt >> 1);
                int vloc = (bt & 1) * 16 + l15;
                int oy = 2 * (ubase + jloc) - 1 + p_y;
                int ox = 2 * (vloc + vbase) - 1 + pq;
                out[((size_t)(n * 32 + co) << 12) + oy * 64 + ox] = lrelu(acc[ct][bt][j] + bv);
            }
        }
    }
}

// ================= VQ =================
__device__ __forceinline__ unsigned order_u32(float s) {
    unsigned u = __float_as_uint(s);
    return (s < 0.f) ? ~u : (u | 0x80000000u);
}

// grid 1024: kb = b&7 (code block of 64), pg = b>>3. enorm computed in-block.
__global__ void __launch_bounds__(256) vq_dist_k(
    const float* __restrict__ z, const float* __restrict__ emb,
    unsigned long long* __restrict__ best)
{
    __shared__ float se[64][64];
    __shared__ float sn[64];
    int b = blockIdx.x;
    int kb = b & 7, pg = b >> 3;
    int tid = threadIdx.x;
    for (int i = tid; i < 4096; i += 256)
        ((float*)se)[i] = emb[(kb << 12) + i];
    if (tid < 64) {
        const float4* e4 = (const float4*)(emb + (((kb << 6) + tid) << 6));
        float s = 0.f;
        #pragma unroll
        for (int j = 0; j < 16; ++j) {
            float4 e = e4[j];
            s = fmaf(e.x, e.x, s); s = fmaf(e.y, e.y, s);
            s = fmaf(e.z, e.z, s); s = fmaf(e.w, e.w, s);
        }
        sn[tid] = s;
    }
    __syncthreads();

    int n = pg >> 1;
    int p0 = ((pg & 1) << 9) + tid;
    size_t base0 = (size_t)n * 65536 + p0;
    float z0[64], z1[64];
    #pragma unroll
    for (int d = 0; d < 64; ++d) z0[d] = z[base0 + (size_t)d * 1024];
    #pragma unroll
    for (int d = 0; d < 64; ++d) z1[d] = z[base0 + 256 + (size_t)d * 1024];

    unsigned long long b0 = ~0ULL, b1 = ~0ULL;
    for (int k = 0; k < 64; ++k) {
        const float4* e4 = (const float4*)se[k];
        float dot0 = 0.f, dot1 = 0.f;
        #pragma unroll
        for (int j = 0; j < 16; ++j) {
            float4 e = e4[j];
            dot0 = fmaf(z0[4*j],   e.x, dot0);
            dot0 = fmaf(z0[4*j+1], e.y, dot0);
            dot0 = fmaf(z0[4*j+2], e.z, dot0);
            dot0 = fmaf(z0[4*j+3], e.w, dot0);
            dot1 = fmaf(z1[4*j],   e.x, dot1);
            dot1 = fmaf(z1[4*j+1], e.y, dot1);
            dot1 = fmaf(z1[4*j+2], e.z, dot1);
            dot1 = fmaf(z1[4*j+3], e.w, dot1);
        }
        float s0 = fmaf(-2.f, dot0, sn[k]);
        float s1 = fmaf(-2.f, dot1, sn[k]);
        unsigned kk = (unsigned)((kb << 6) + k);
        unsigned long long p0k = ((unsigned long long)order_u32(s0) << 32) | kk;
        unsigned long long p1k = ((unsigned long long)order_u32(s1) << 32) | kk;
        b0 = p0k < b0 ? p0k : b0;
        b1 = p1k < b1 ? p1k : b1;
    }
    size_t m0 = ((size_t)pg << 9) + tid;
    best[((size_t)kb << 16) + m0]       = b0;
    best[((size_t)kb << 16) + m0 + 256] = b1;
}

// grid 256: per-pixel min over 8 code-blocks; writes out_q (NCHW fp32) AND tbuf (NHWC bf16)
__global__ void __launch_bounds__(256) vq_combine_k(
    const float* __restrict__ z, const float* __restrict__ emb,
    const unsigned long long* __restrict__ best,
    float* __restrict__ out_q, unsigned short* __restrict__ outT,
    float* __restrict__ partials)
{
    __shared__ unsigned tq32[256][33];
    __shared__ float sh[256];
    int tid = threadIdx.x;
    int m = blockIdx.x * 256 + tid;
    unsigned long long bb = best[m];
    #pragma unroll
    for (int kb = 1; kb < 8; ++kb) {
        unsigned long long v = best[((size_t)kb << 16) + m];
        bb = v < bb ? v : bb;
    }
    int bi = (int)(bb & 0x1ffu);
    int n = m >> 10, p = m & 1023;
    size_t base = (size_t)n * 65536 + p;
    const float* eb = emb + (bi << 6);
    float lsum = 0.f;
    #pragma unroll
    for (int d = 0; d < 64; d += 2) {
        float z0 = z[base + (size_t)d * 1024];
        float z1 = z[base + (size_t)(d + 1) * 1024];
        float q0 = eb[d], q1 = eb[d + 1];
        out_q[base + (size_t)d * 1024]       = q0;
        out_q[base + (size_t)(d + 1) * 1024] = q1;
        float d0 = q0 - z0, d1 = q1 - z1;
        lsum = fmaf(d0, d0, lsum);
        lsum = fmaf(d1, d1, lsum);
        tq32[tid][d >> 1] = (unsigned)f2bf(q0) | ((unsigned)f2bf(q1) << 16);
    }
    sh[tid] = lsum;
    __syncthreads();
    // coalesced NHWC bf16 write: block covers pixels [m0, m0+256)
    unsigned* oT = (unsigned*)outT;
    size_t m0 = (size_t)blockIdx.x * 256;
    #pragma unroll
    for (int k = 0; k < 32; ++k) {
        int j = k * 256 + tid;
        int px = j >> 5, c = j & 31;
        oT[(m0 + px) * 32 + c] = tq32[px][c];
    }
    for (int st = 128; st > 0; st >>= 1) {
        if (tid < st) sh[tid] += sh[tid + st];
        __syncthreads();
    }
    if (tid == 0) partials[blockIdx.x] = sh[0];
}

__global__ void vq_fin_k(const float* __restrict__ partials, float* __restrict__ out)
{
    __shared__ float sh[256];
    sh[threadIdx.x] = partials[threadIdx.x];
    __syncthreads();
    for (int st = 128; st > 0; st >>= 1) {
        if (threadIdx.x < st) sh[threadIdx.x] += sh[threadIdx.x + st];
        __syncthreads();
    }
    if (threadIdx.x == 0) out[0] = sh[0] * (0.25f / (65536.f * 64.f));
}

// ================= dt2: deconv 32->3, 64x64 -> 128x128, tanh (fp32) =================
// grid 2048: n = b&63, rt = b>>6 (32 tiles of 4 rows). thread: r4 = tid>>6, g = tid&63 (2 px)
__global__ void __launch_bounds__(256) deconv_dt2_t(
    const float* __restrict__ in, const float* __restrict__ w,
    const float* __restrict__ bias, float* __restrict__ out)
{
    __shared__ float lin[8][4][67];
    __shared__ float lw[8][3][16];
    int b = blockIdx.x;
    int n = b & 63, rt = b >> 6;
    int tid = threadIdx.x;
    int r4 = tid >> 6, g = tid & 63;
    int oy = rt * 4 + r4;
    const float* inp = in + (size_t)n * 32 * 4096;
    int iy0 = 2 * rt - 1;
    int ky0 = (oy + 1) & 1;
    int iyA = ((oy + 1 - ky0) >> 1) - iy0;
    int iyB = iyA - 1;

    // edge cols always zero
    if (tid < 64) lin[tid >> 3][(tid >> 1) & 3][(tid & 1) ? 65 : 0] = 0.f;

    float acc[3][2];
    #pragma unroll
    for (int co = 0; co < 3; ++co) { acc[co][0] = acc[co][1] = 0.f; }

    int scol = tid & 63, srs = tid >> 6;
    for (int cic = 0; cic < 4; ++cic) {
        __syncthreads();
        // main staging: div-free, 64-wide coalesced
        {
            int gy = iy0 + srs;
            bool ok = (gy >= 0 && gy < 64);
            #pragma unroll
            for (int k = 0; k < 8; ++k) {
                float v = ok ? inp[(cic * 8 + k) * 4096 + gy * 64 + scol] : 0.f;
                lin[k][srs][scol + 1] = v;
            }
        }
        if (tid < 128) {
            int ci = tid >> 4, tt = tid & 15;
            #pragma unroll
            for (int co = 0; co < 3; ++co)
                lw[ci][co][tt] = w[((cic * 8 + ci) * 3 + co) * 16 + tt];
        }
        __syncthreads();
        #pragma unroll 2
        for (int ci = 0; ci < 8; ++ci) {
            float vA0 = lin[ci][iyA][g],     vA1 = lin[ci][iyA][g + 1], vA2 = lin[ci][iyA][g + 2];
            float vB0 = lin[ci][iyB][g],     vB1 = lin[ci][iyB][g + 1], vB2 = lin[ci][iyB][g + 2];
            #pragma unroll
            for (int co = 0; co < 3; ++co) {
                const float4* wp = (const float4*)lw[ci][co];
                float4 wA = wp[ky0];
                float4 wB = wp[ky0 + 2];
                acc[co][0] = fmaf(vA1, wA.y, fmaf(vA0, wA.w, fmaf(vB1, wB.y, fmaf(vB0, wB.w, acc[co][0]))));
                acc[co][1] = fmaf(vA2, wA.x, fmaf(vA1, wA.z, fmaf(vB2, wB.x, fmaf(vB1, wB.z, acc[co][1]))));
            }
        }
    }
    #pragma unroll
    for (int co = 0; co < 3; ++co) {
        float bv = bias[co];
        float2 v;
        v.x = fast_tanh(acc[co][0] + bv);
        v.y = fast_tanh(acc[co][1] + bv);
        *(float2*)(out + ((size_t)(n * 3 + co) * 16384) + oy * 128 + 2 * g) = v;
    }
}

extern "C" void kernel_launch(void* const* d_in, const int* in_sizes, int n_in,
                              void* d_out, int out_size, void* d_ws, size_t ws_size,
                              hipStream_t stream)
{
    const float* x    = (const float*)d_in[0];
    const float* e1w  = (const float*)d_in[1];
    const float* e1b  = (const float*)d_in[2];
    const float* e2w  = (const float*)d_in[3];
    const float* e2b  = (const float*)d_in[4];
    const float* e3w  = (const float*)d_in[5];
    const float* e3b  = (const float*)d_in[6];
    const float* er1w = (const float*)d_in[7];
    const float* er1g = (const float*)d_in[8];
    const float* er1b = (const float*)d_in[9];
    const float* er2w = (const float*)d_in[10];
    const float* er2g = (const float*)d_in[11];
    const float* er2b = (const float*)d_in[12];
    const float* e4w  = (const float*)d_in[13];
    const float* e4b  = (const float*)d_in[14];
    const float* emb  = (const float*)d_in[15];
    const float* d1w  = (const float*)d_in[16];
    const float* d1b  = (const float*)d_in[17];
    const float* dr1w = (const float*)d_in[18];
    const float* dr1g = (const float*)d_in[19];
    const float* dr1b = (const float*)d_in[20];
    const float* dr2w = (const float*)d_in[21];
    const float* dr2g = (const float*)d_in[22];
    const float* dr2b = (const float*)d_in[23];
    const float* dt1w = (const float*)d_in[24];
    const float* dt1b = (const float*)d_in[25];
    const float* dt2w = (const float*)d_in[26];
    const float* dt2b = (const float*)d_in[27];

    float* out = (float*)d_out;
    float* ws  = (float*)d_ws;

    // workspace layout (floats)
    float* B0 = ws;                   // 8,388,608
    float* B1 = ws + 8388608;         // 4,194,304
    float* B2 = B1 + 4194304;
    float* B3 = B2 + 4194304;
    float* B4 = B3 + 4194304;
    float* psum   = B4 + 4194304;     // 16384
    float* pss    = psum + 16384;     // 16384
    float* fin    = pss + 16384;      // 128
    float* vq_part = fin + 128;       // 256
    float* enorm   = vq_part + 256;   // 512 (unused now)
    unsigned long long* bestbuf = (unsigned long long*)(enorm + 512);  // 4MB

    unsigned short* tbuf = (unsigned short*)B1;  // 8.4MB bf16 NHWC (decoder phase)

    float* out_recon = out;                 // 3,145,728
    float* out_q     = out + 3145728;       // 4,194,304
    float* out_e     = out + 7340032;       // 4,194,304 (scratch for e2 partial until e4 overwrites)
    float* out_loss  = out + 11534336;      // 1

    const float invM = 1.f / 65536.f;

    // ---------------- encoder (fp32 — protects VQ argmin) ----------------
    conv_e1_t<<<1024, 256, 0, stream>>>(x, e1w, e1b, B0);
    conv_e2p_k<<<1024, 256, 0, stream>>>(B0, e2w, B1, out_e);
    conv3x3_t<1,1,0><<<512, 256, 0, stream>>>(B1, out_e, e2b, e3w, e3b, B2, nullptr, nullptr);

    conv3x3_t<0,0,1><<<512, 256, 0, stream>>>(B2, nullptr, nullptr, er1w, nullptr, B3, psum, pss);
    bn_fin2_k<<<1, 64, 0, stream>>>(psum, pss, fin, invM, 64);
    conv1x1_t<1,0,1><<<512, 256, 0, stream>>>(B3, nullptr, er2w, nullptr, fin, er1g, er1b, B4, psum, pss);
    bn_fin2_k<<<1, 64, 0, stream>>>(psum, pss, fin, invM, 64);
    conv1x1_t<2,1,0><<<512, 256, 0, stream>>>(B4, B2, e4w, e4b, fin, er2g, er2b, out_e, nullptr, nullptr);

    // VQ (fp32); combine also emits NHWC bf16 tbuf for the decoder
    vq_dist_k<<<1024, 256, 0, stream>>>(out_e, emb, bestbuf);
    vq_combine_k<<<256, 256, 0, stream>>>(out_e, emb, bestbuf, out_q, tbuf, vq_part);
    vq_fin_k<<<1, 256, 0, stream>>>(vq_part, out_loss);

    // ---------------- decoder (bf16 MFMA) ----------------
    mfma_conv3x3_k<1,0><<<512, 256, 0, stream>>>(tbuf, d1w, d1b, B2, nullptr, nullptr);

    trans_k<0><<<256, 256, 0, stream>>>(B2, nullptr, nullptr, nullptr, tbuf);
    mfma_conv3x3_k<0,1><<<512, 256, 0, stream>>>(tbuf, dr1w, nullptr, B3, psum, pss);
    bn_fin3_k<<<1, 64, 0, stream>>>(psum, pss, fin, invM);

    trans_k<1><<<256, 256, 0, stream>>>(B3, fin, dr1g, dr1b, tbuf);
    mfma_conv1x1_k<0,1><<<512, 256, 0, stream>>>(tbuf, dr2w, nullptr, B4, psum, pss);
    bn_fin3_k<<<1, 64, 0, stream>>>(psum, pss, fin, invM);

    bnres_trans_k<<<256, 256, 0, stream>>>(B4, B2, fin, dr2g, dr2b, tbuf);
    mfma_dt1_k<<<1024, 256, 0, stream>>>(tbuf, dt1w, dt1b, B0);

    deconv_dt2_t<<<2048, 256, 0, stream>>>(B0, dt2w, dt2b, out_recon);
}

// Round 13
// 541.878 us; speedup vs baseline: 1.2025x; 1.0767x over previous
//
#include <hip/hip_runtime.h>
#include <math.h>

#define LREL 0.01f
__device__ __forceinline__ float lrelu(float x) { return x > 0.f ? x : LREL * x; }
__device__ __forceinline__ float fast_tanh(float x) {
    x = fminf(fmaxf(x, -10.f), 10.f);
    float a = __expf(2.f * x);
    return (a - 1.f) / (a + 1.f);
}
__device__ __forceinline__ unsigned short f2bf(float f) {
    unsigned u = __float_as_uint(f);
    unsigned r = u + 0x7FFFu + ((u >> 16) & 1u);
    return (unsigned short)(r >> 16);
}
__device__ __forceinline__ float bf2f(unsigned short h) {
    return __uint_as_float(((unsigned)h) << 16);
}

typedef __attribute__((ext_vector_type(8))) short short8;
typedef __attribute__((ext_vector_type(4))) float f32x4;

// ================= e1: 3->32, 128x128 -> 64x64, 4x4 s2 p1, lrelu (fp32) =================
__global__ void __launch_bounds__(256) conv_e1_t(
    const float* __restrict__ x, const float* __restrict__ w,
    const float* __restrict__ bias, float* __restrict__ out)
{
    __shared__ float lin[3][18][131];
    __shared__ float lw[3][16][16];
    int b = blockIdx.x;
    int n = b & 63, t = b >> 6;
    int rt = t & 7, cg = t >> 3;
    int tid = threadIdx.x;
    int r = tid >> 5, g = tid & 31;
    const float* inp = x + (size_t)n * 3 * 16384;

    #pragma unroll
    for (int ci = 0; ci < 3; ++ci)
        if (tid < 36) lin[ci][tid >> 1][(tid & 1) ? 129 : 0] = 0.f;
    #pragma unroll
    for (int ci = 0; ci < 3; ++ci)
        #pragma unroll
        for (int k = 0; k < 9; ++k) {
            int idx = k * 256 + tid;
            int row = idx >> 7, col = idx & 127;
            int gy = 16 * rt - 1 + row;
            float v = 0.f;
            if (gy >= 0 && gy < 128)
                v = inp[ci * 16384 + gy * 128 + col];
            lin[ci][row][col + 1] = v;
        }
    for (int i = tid; i < 768; i += 256) {
        int ci = i >> 8, rr = i & 255, co = rr >> 4, tt = rr & 15;
        lw[ci][co][tt] = w[((cg * 16 + co) * 3 + ci) * 16 + tt];
    }
    __syncthreads();

    float acc[16][2];
    #pragma unroll
    for (int co = 0; co < 16; ++co) { acc[co][0] = acc[co][1] = 0.f; }

    #pragma unroll
    for (int ci = 0; ci < 3; ++ci) {
        float win[4][6];
        #pragma unroll
        for (int ky = 0; ky < 4; ++ky)
            #pragma unroll
            for (int dx = 0; dx < 6; ++dx)
                win[ky][dx] = lin[ci][2 * r + ky][4 * g + dx];
        #pragma unroll
        for (int co = 0; co < 16; ++co) {
            #pragma unroll
            for (int ky = 0; ky < 4; ++ky)
                #pragma unroll
                for (int kx = 0; kx < 4; ++kx) {
                    float wv = lw[ci][co][ky * 4 + kx];
                    acc[co][0] = fmaf(win[ky][kx],     wv, acc[co][0]);
                    acc[co][1] = fmaf(win[ky][kx + 2], wv, acc[co][1]);
                }
        }
    }
    int oy = 8 * rt + r;
    #pragma unroll
    for (int co = 0; co < 16; ++co) {
        float bv = bias[cg * 16 + co];
        float2 v;
        v.x = lrelu(acc[co][0] + bv);
        v.y = lrelu(acc[co][1] + bv);
        *(float2*)(out + ((size_t)(n * 32 + cg * 16 + co) << 12) + oy * 64 + 2 * g) = v;
    }
}

// ================= e2 partial: 32->64, 64x64 -> 32x32, 16-ci halves, no bias/act =================
__global__ void __launch_bounds__(256) conv_e2p_k(
    const float* __restrict__ in, const float* __restrict__ w,
    float* __restrict__ outA, float* __restrict__ outB)
{
    __shared__ float lin[4][10][66];
    __shared__ float lw[4][64][16];
    int b = blockIdx.x;
    int n = b & 63, ry = (b >> 6) & 7, ch = b >> 9;
    int tid = threadIdx.x;
    int c = tid & 31, cog = tid >> 5;
    int iy0 = 8 * ry - 1;
    const float* inp = in + (size_t)n * 32 * 4096;
    float* outp = (ch ? outB : outA);

    #pragma unroll
    for (int ci = 0; ci < 4; ++ci)
        if (tid < 20) lin[ci][tid >> 1][(tid & 1) ? 65 : 0] = 0.f;

    float acc[8][4];
    #pragma unroll
    for (int q = 0; q < 8; ++q) { acc[q][0]=acc[q][1]=acc[q][2]=acc[q][3]=0.f; }

    int scol = tid & 63, srs = tid >> 6;
    for (int cic = 0; cic < 4; ++cic) {
        __syncthreads();
        #pragma unroll
        for (int k = 0; k < 3; ++k) {
            int row = k * 4 + srs;
            if (row < 10) {
                int gy = iy0 + row;
                #pragma unroll
                for (int ci = 0; ci < 4; ++ci) {
                    float v = 0.f;
                    if (gy >= 0 && gy < 64)
                        v = inp[(ch * 16 + cic * 4 + ci) * 4096 + gy * 64 + scol];
                    lin[ci][row][scol + 1] = v;
                }
            }
        }
        for (int i = tid; i < 4096; i += 256) {
            int ci = i >> 10, rr = i & 1023, co = rr >> 4, tt = rr & 15;
            lw[ci][co][tt] = w[(co * 32 + ch * 16 + cic * 4 + ci) * 16 + tt];
        }
        __syncthreads();
        #pragma unroll
        for (int ci = 0; ci < 4; ++ci) {
            float win[10][4];
            #pragma unroll
            for (int riy = 0; riy < 10; ++riy)
                #pragma unroll
                for (int q = 0; q < 4; ++q)
                    win[riy][q] = lin[ci][riy][2 * c + q];
            #pragma unroll
            for (int cq = 0; cq < 8; ++cq) {
                const float* wp = lw[ci][cog * 8 + cq];
                #pragma unroll
                for (int r = 0; r < 4; ++r)
                    #pragma unroll
                    for (int ky = 0; ky < 4; ++ky)
                        #pragma unroll
                        for (int kx = 0; kx < 4; ++kx)
                            acc[cq][r] = fmaf(win[2 * r + ky][kx], wp[ky * 4 + kx], acc[cq][r]);
            }
        }
    }
    #pragma unroll
    for (int cq = 0; cq < 8; ++cq) {
        int co = cog * 8 + cq;
        #pragma unroll
        for (int r = 0; r < 4; ++r)
            outp[((size_t)(n * 64 + co) << 10) + (4 * ry + r) * 32 + c] = acc[cq][r];
    }
}

// ================= conv1x1 fp32 (encoder), fused BN input / stats =================
template<int IN, int ACT, int STATS>
__global__ void __launch_bounds__(256) conv1x1_t(
    const float* __restrict__ in, const float* __restrict__ res,
    const float* __restrict__ w, const float* __restrict__ bias,
    const float* __restrict__ fin, const float* __restrict__ g,
    const float* __restrict__ beta, float* __restrict__ out,
    float* __restrict__ psum, float* __restrict__ pss)
{
    __shared__ float lw[64][8];
    __shared__ float sga[64], sbb[64];
    __shared__ float sS[8][4], sQ[8][4];
    int b = blockIdx.x;
    int n = b & 63, cg = b >> 6;
    int tid = threadIdx.x;
    int lane = tid & 63, wv_id = tid >> 6;
    for (int i = tid; i < 512; i += 256) {
        int ci = i >> 3, co = i & 7;
        lw[ci][co] = w[(cg * 8 + co) * 64 + ci];
    }
    if (IN >= 1 && tid < 64) {
        float ga = g[tid] * fin[2 * tid + 1];
        sga[tid] = ga;
        sbb[tid] = beta[tid] - fin[2 * tid] * ga;
    }
    __syncthreads();
    const float4* in4 = (const float4*)(in + (size_t)n * 65536);
    const float4* res4 = (IN == 2) ? (const float4*)(res + (size_t)n * 65536) : nullptr;
    float acc[8][4];
    #pragma unroll
    for (int co = 0; co < 8; ++co) { acc[co][0]=acc[co][1]=acc[co][2]=acc[co][3]=0.f; }
    #pragma unroll 4
    for (int ci = 0; ci < 64; ++ci) {
        float4 xv = in4[(ci << 8) + tid];
        float x0, x1, x2, x3;
        if (IN == 1) {
            float ga = sga[ci], bb = sbb[ci];
            x0 = fmaxf(fmaf(xv.x, ga, bb), 0.f);
            x1 = fmaxf(fmaf(xv.y, ga, bb), 0.f);
            x2 = fmaxf(fmaf(xv.z, ga, bb), 0.f);
            x3 = fmaxf(fmaf(xv.w, ga, bb), 0.f);
        } else if (IN == 2) {
            float4 rv = res4[(ci << 8) + tid];
            float ga = sga[ci], bb = sbb[ci];
            x0 = lrelu(rv.x + fmaf(xv.x, ga, bb));
            x1 = lrelu(rv.y + fmaf(xv.y, ga, bb));
            x2 = lrelu(rv.z + fmaf(xv.z, ga, bb));
            x3 = lrelu(rv.w + fmaf(xv.w, ga, bb));
        } else {
            x0 = xv.x; x1 = xv.y; x2 = xv.z; x3 = xv.w;
        }
        #pragma unroll
        for (int co = 0; co < 8; ++co) {
            float wvv = lw[ci][co];
            acc[co][0] = fmaf(x0, wvv, acc[co][0]);
            acc[co][1] = fmaf(x1, wvv, acc[co][1]);
            acc[co][2] = fmaf(x2, wvv, acc[co][2]);
            acc[co][3] = fmaf(x3, wvv, acc[co][3]);
        }
    }
    #pragma unroll
    for (int co = 0; co < 8; ++co) {
        float bv = bias ? bias[cg * 8 + co] : 0.f;
        float a0 = acc[co][0] + bv, a1 = acc[co][1] + bv, a2 = acc[co][2] + bv, a3 = acc[co][3] + bv;
        if (ACT == 1) { a0 = lrelu(a0); a1 = lrelu(a1); a2 = lrelu(a2); a3 = lrelu(a3); }
        float4 v; v.x = a0; v.y = a1; v.z = a2; v.w = a3;
        ((float4*)(out + (size_t)n * 65536 + (size_t)(cg * 8 + co) * 1024))[tid] = v;
        if (STATS) {
            float s = a0 + a1 + a2 + a3;
            float q = a0*a0 + a1*a1 + a2*a2 + a3*a3;
            #pragma unroll
            for (int m = 1; m < 64; m <<= 1) {
                s += __shfl_xor(s, m);
                q += __shfl_xor(q, m);
            }
            if (lane == 0) { sS[co][wv_id] = s; sQ[co][wv_id] = q; }
        }
    }
    if (STATS) {
        __syncthreads();
        if (tid < 8) {
            float s = sS[tid][0] + sS[tid][1] + sS[tid][2] + sS[tid][3];
            float q = sQ[tid][0] + sQ[tid][1] + sQ[tid][2] + sQ[tid][3];
            psum[(cg * 8 + tid) * 64 + n] = s;
            pss [(cg * 8 + tid) * 64 + n] = q;
        }
    }
}

// ================= BN finalize from per-(c, slice) partials =================
__global__ void bn_fin2_k(const float* __restrict__ psum, const float* __restrict__ pss,
                          float* __restrict__ fin, float invM, int cnt)
{
    int c = threadIdx.x;
    if (c >= 64) return;
    float s = 0.f, q = 0.f;
    for (int i = 0; i < cnt; ++i) { s += psum[c * cnt + i]; q += pss[c * cnt + i]; }
    float mean = s * invM;
    float var  = q * invM - mean * mean;
    fin[2 * c] = mean;
    fin[2 * c + 1] = rsqrtf(var + 1e-5f);
}

__global__ void bn_fin3_k(const float* __restrict__ psum, const float* __restrict__ pss,
                          float* __restrict__ fin, float invM)
{
    int c = threadIdx.x;
    if (c >= 64) return;
    float s = 0.f, q = 0.f;
    for (int i = 0; i < 256; ++i) { s += psum[c * 256 + i]; q += pss[c * 256 + i]; }
    float mean = s * invM;
    float var  = q * invM - mean * mean;
    fin[2 * c] = mean;
    fin[2 * c + 1] = rsqrtf(var + 1e-5f);
}

// ================= transpose NCHW fp32 -> NHWC bf16 (+optional BN-relu) =================
template<int MODE>
__global__ void __launch_bounds__(256) trans_k(
    const float* __restrict__ in, const float* __restrict__ fin,
    const float* __restrict__ g, const float* __restrict__ beta,
    unsigned short* __restrict__ outT)
{
    __shared__ unsigned short tt[256][68];
    __shared__ float sga[64], sbb[64];
    int b = blockIdx.x;
    int n = b >> 2, pxb = b & 3;
    int tid = threadIdx.x;
    if (MODE == 1) {
        if (tid < 64) {
            float ga = g[tid] * fin[2 * tid + 1];
            sga[tid] = ga;
            sbb[tid] = beta[tid] - fin[2 * tid] * ga;
        }
        __syncthreads();
    }
    for (int i = tid; i < 16384; i += 256) {
        int ci = i >> 8, px = i & 255;
        float v = in[((size_t)(n * 64 + ci) << 10) + pxb * 256 + px];
        if (MODE == 1) v = fmaxf(fmaf(v, sga[ci], sbb[ci]), 0.f);
        tt[px][ci] = f2bf(v);
    }
    __syncthreads();
    for (int o = tid; o < 4096; o += 256) {
        int px = o >> 4, c4 = o & 15;
        uint2 v = *(const uint2*)&tt[px][c4 * 4];
        *(uint2*)(outT + ((((size_t)n << 10) + pxb * 256 + px) << 6) + c4 * 4) = v;
    }
}

// ======= split-bf16 transpose: NCHW fp32 -> NHWC bf16 hi + lo =======
// INM 0: plain in ; INM 1: lrelu(A + B + bias2)
template<int INM>
__global__ void __launch_bounds__(256) trans_hl_k(
    const float* __restrict__ inA, const float* __restrict__ inB,
    const float* __restrict__ bias2,
    unsigned short* __restrict__ outH, unsigned short* __restrict__ outL)
{
    __shared__ unsigned short th[256][68];
    __shared__ unsigned short tl[256][68];
    __shared__ float sb[64];
    int b = blockIdx.x;
    int n = b >> 2, pxb = b & 3;
    int tid = threadIdx.x;
    if (INM == 1 && tid < 64) sb[tid] = bias2[tid];
    if (INM == 1) __syncthreads();
    for (int i = tid; i < 16384; i += 256) {
        int ci = i >> 8, px = i & 255;
        size_t gi = ((size_t)(n * 64 + ci) << 10) + pxb * 256 + px;
        float v = inA[gi];
        if (INM == 1) v = lrelu(v + inB[gi] + sb[ci]);
        unsigned short h = f2bf(v);
        th[px][ci] = h;
        tl[px][ci] = f2bf(v - bf2f(h));
    }
    __syncthreads();
    for (int o = tid; o < 4096; o += 256) {
        int px = o >> 4, c4 = o & 15;
        size_t oidx = ((((size_t)n << 10) + pxb * 256 + px) << 6) + c4 * 4;
        *(uint2*)(outH + oidx) = *(const uint2*)&th[px][c4 * 4];
        *(uint2*)(outL + oidx) = *(const uint2*)&tl[px][c4 * 4];
    }
}

// ================= fused lrelu(res + bn(x)) + NCHW fp32 -> NHWC bf16 =================
__global__ void __launch_bounds__(256) bnres_trans_k(
    const float* __restrict__ xin, const float* __restrict__ res,
    const float* __restrict__ fin, const float* __restrict__ g,
    const float* __restrict__ beta, unsigned short* __restrict__ outT)
{
    __shared__ unsigned short tt[256][68];
    __shared__ float sga[64], sbb[64];
    int b = blockIdx.x;
    int n = b >> 2, pxb = b & 3;
    int tid = threadIdx.x;
    if (tid < 64) {
        float ga = g[tid] * fin[2 * tid + 1];
        sga[tid] = ga;
        sbb[tid] = beta[tid] - fin[2 * tid] * ga;
    }
    __syncthreads();
    for (int i = tid; i < 16384; i += 256) {
        int ci = i >> 8, px = i & 255;
        size_t gi = ((size_t)(n * 64 + ci) << 10) + pxb * 256 + px;
        float v = lrelu(res[gi] + fmaf(xin[gi], sga[ci], sbb[ci]));
        tt[px][ci] = f2bf(v);
    }
    __syncthreads();
    for (int o = tid; o < 4096; o += 256) {
        int px = o >> 4, c4 = o & 15;
        uint2 v = *(const uint2*)&tt[px][c4 * 4];
        *(uint2*)(outT + ((((size_t)n << 10) + pxb * 256 + px) << 6) + c4 * 4) = v;
    }
}

// ================= MFMA conv3x3 64->64 @32x32, bf16 (decoder) =================
template<int ACT, int STATS>
__global__ void __launch_bounds__(256) mfma_conv3x3_k(
    const unsigned short* __restrict__ inT, const float* __restrict__ w,
    const float* __restrict__ bias, float* __restrict__ out,
    float* __restrict__ psum, float* __restrict__ pss)
{
    __shared__ unsigned short lin[10][34][40];
    __shared__ unsigned short lwA[32][296];
    __shared__ float sS[4][32], sQ[4][32];
    int b = blockIdx.x;
    int cg = b & 1, pxb = (b >> 1) & 3, n = b >> 3;
    int tid = threadIdx.x;
    int wv = tid >> 6, l = tid & 63;
    int l15 = l & 15, lhi = l >> 4;

    f32x4 acc[2][4];
    #pragma unroll
    for (int ct = 0; ct < 2; ++ct)
        #pragma unroll
        for (int bt = 0; bt < 4; ++bt) {
            f32x4 z = {0.f, 0.f, 0.f, 0.f};
            acc[ct][bt] = z;
        }

    for (int c2 = 0; c2 < 2; ++c2) {
        __syncthreads();
        for (int i = tid; i < 1360; i += 256) {
            int pos = i >> 2, q = i & 3;
            int row = pos / 34, col = pos % 34;
            int iy = pxb * 8 - 1 + row, ix = col - 1;
            uint4 v = make_uint4(0u, 0u, 0u, 0u);
            if (iy >= 0 && iy < 32 && ix >= 0 && ix < 32)
                v = *(const uint4*)(inT + ((((size_t)n << 10) + iy * 32 + ix) << 6) + c2 * 32 + q * 8);
            *(uint4*)&lin[row][col][q * 8] = v;
        }
        for (int i = tid; i < 9216; i += 256) {
            int col = i / 288, k = i % 288;
            int tap = k >> 5, cc = k & 31;
            int co = cg * 32 + col;
            lwA[col][k] = f2bf(w[(co * 64 + c2 * 32 + cc) * 9 + tap]);
        }
        __syncthreads();
        #pragma unroll
        for (int tap = 0; tap < 9; ++tap) {
            const int dy = tap / 3, dx = tap % 3;
            short8 a[2], bb[4];
            #pragma unroll
            for (int ct = 0; ct < 2; ++ct)
                a[ct] = *(const short8*)&lwA[ct * 16 + l15][tap * 32 + lhi * 8];
            #pragma unroll
            for (int bt = 0; bt < 4; ++bt) {
                int rr = 2 * wv + (bt >> 1);
                int cc0 = (bt & 1) * 16;
                bb[bt] = *(const short8*)&lin[rr + dy][cc0 + l15 + dx][lhi * 8];
            }
            #pragma unroll
            for (int ct = 0; ct < 2; ++ct)
                #pragma unroll
                for (int bt = 0; bt < 4; ++bt)
                    acc[ct][bt] = __builtin_amdgcn_mfma_f32_16x16x32_bf16(a[ct], bb[bt], acc[ct][bt], 0, 0, 0);
        }
    }

    int orow0 = pxb * 8 + 2 * wv;
    #pragma unroll
    for (int ct = 0; ct < 2; ++ct) {
        #pragma unroll
        for (int j = 0; j < 4; ++j) {
            int co_l = ct * 16 + lhi * 4 + j;
            int co = cg * 32 + co_l;
            float bv = bias ? bias[co] : 0.f;
            float s = 0.f, q = 0.f;
            #pragma unroll
            for (int bt = 0; bt < 4; ++bt) {
                float v = acc[ct][bt][j] + bv;
                if (ACT == 1) v = lrelu(v);
                int row = orow0 + (bt >> 1);
                int col = (bt & 1) * 16 + l15;
                out[(((size_t)n * 64 + co) << 10) + row * 32 + col] = v;
                if (STATS) { s += v; q = fmaf(v, v, q); }
            }
            if (STATS) {
                #pragma unroll
                for (int m = 1; m < 16; m <<= 1) {
                    s += __shfl_xor(s, m);
                    q += __shfl_xor(q, m);
                }
                if (l15 == 0) { sS[wv][co_l] = s; sQ[wv][co_l] = q; }
            }
        }
    }
    if (STATS) {
        __syncthreads();
        if (tid < 32) {
            float s = sS[0][tid] + sS[1][tid] + sS[2][tid] + sS[3][tid];
            float q = sQ[0][tid] + sQ[1][tid] + sQ[2][tid] + sQ[3][tid];
            psum[(cg * 32 + tid) * 256 + n * 4 + pxb] = s;
            pss [(cg * 32 + tid) * 256 + n * 4 + pxb] = q;
        }
    }
}

// ======= split-bf16 MFMA conv3x3 (encoder, fp32-grade accuracy) =======
// acc = Whi*Xhi + Whi*Xlo + Wlo*Xhi ; grid 512: cg=b&1, pxb=(b>>1)&3, n=b>>3
template<int ACT, int STATS>
__global__ void __launch_bounds__(256) mfma_conv3x3_hl_k(
    const unsigned short* __restrict__ inH, const unsigned short* __restrict__ inL,
    const float* __restrict__ w, const float* __restrict__ bias,
    float* __restrict__ out, float* __restrict__ psum, float* __restrict__ pss)
{
    __shared__ unsigned short linH[10][34][40];
    __shared__ unsigned short linL[10][34][40];
    __shared__ unsigned short lwH[32][296];
    __shared__ unsigned short lwL[32][296];
    __shared__ float sS[4][32], sQ[4][32];
    int b = blockIdx.x;
    int cg = b & 1, pxb = (b >> 1) & 3, n = b >> 3;
    int tid = threadIdx.x;
    int wv = tid >> 6, l = tid & 63;
    int l15 = l & 15, lhi = l >> 4;

    f32x4 acc[2][4];
    #pragma unroll
    for (int ct = 0; ct < 2; ++ct)
        #pragma unroll
        for (int bt = 0; bt < 4; ++bt) {
            f32x4 z = {0.f, 0.f, 0.f, 0.f};
            acc[ct][bt] = z;
        }

    for (int c2 = 0; c2 < 2; ++c2) {
        __syncthreads();
        for (int i = tid; i < 1360; i += 256) {
            int pos = i >> 2, q = i & 3;
            int row = pos / 34, col = pos % 34;
            int iy = pxb * 8 - 1 + row, ix = col - 1;
            uint4 vh = make_uint4(0u, 0u, 0u, 0u);
            uint4 vl = make_uint4(0u, 0u, 0u, 0u);
            if (iy >= 0 && iy < 32 && ix >= 0 && ix < 32) {
                size_t gi = ((((size_t)n << 10) + iy * 32 + ix) << 6) + c2 * 32 + q * 8;
                vh = *(const uint4*)(inH + gi);
                vl = *(const uint4*)(inL + gi);
            }
            *(uint4*)&linH[row][col][q * 8] = vh;
            *(uint4*)&linL[row][col][q * 8] = vl;
        }
        for (int i = tid; i < 9216; i += 256) {
            int col = i / 288, k = i % 288;
            int tap = k >> 5, cc = k & 31;
            int co = cg * 32 + col;
            float wv0 = w[(co * 64 + c2 * 32 + cc) * 9 + tap];
            unsigned short h = f2bf(wv0);
            lwH[col][k] = h;
            lwL[col][k] = f2bf(wv0 - bf2f(h));
        }
        __syncthreads();
        #pragma unroll
        for (int tap = 0; tap < 9; ++tap) {
            const int dy = tap / 3, dx = tap % 3;
            short8 aH[2], aL[2], bH[4], bL[4];
            #pragma unroll
            for (int ct = 0; ct < 2; ++ct) {
                aH[ct] = *(const short8*)&lwH[ct * 16 + l15][tap * 32 + lhi * 8];
                aL[ct] = *(const short8*)&lwL[ct * 16 + l15][tap * 32 + lhi * 8];
            }
            #pragma unroll
            for (int bt = 0; bt < 4; ++bt) {
                int rr = 2 * wv + (bt >> 1);
                int cc0 = (bt & 1) * 16;
                bH[bt] = *(const short8*)&linH[rr + dy][cc0 + l15 + dx][lhi * 8];
                bL[bt] = *(const short8*)&linL[rr + dy][cc0 + l15 + dx][lhi * 8];
            }
            #pragma unroll
            for (int ct = 0; ct < 2; ++ct)
                #pragma unroll
                for (int bt = 0; bt < 4; ++bt) {
                    acc[ct][bt] = __builtin_amdgcn_mfma_f32_16x16x32_bf16(aH[ct], bH[bt], acc[ct][bt], 0, 0, 0);
                    acc[ct][bt] = __builtin_amdgcn_mfma_f32_16x16x32_bf16(aH[ct], bL[bt], acc[ct][bt], 0, 0, 0);
                    acc[ct][bt] = __builtin_amdgcn_mfma_f32_16x16x32_bf16(aL[ct], bH[bt], acc[ct][bt], 0, 0, 0);
                }
        }
    }

    int orow0 = pxb * 8 + 2 * wv;
    #pragma unroll
    for (int ct = 0; ct < 2; ++ct) {
        #pragma unroll
        for (int j = 0; j < 4; ++j) {
            int co_l = ct * 16 + lhi * 4 + j;
            int co = cg * 32 + co_l;
            float bv = bias ? bias[co] : 0.f;
            float s = 0.f, q = 0.f;
            #pragma unroll
            for (int bt = 0; bt < 4; ++bt) {
                float v = acc[ct][bt][j] + bv;
                if (ACT == 1) v = lrelu(v);
                int row = orow0 + (bt >> 1);
                int col = (bt & 1) * 16 + l15;
                out[(((size_t)n * 64 + co) << 10) + row * 32 + col] = v;
                if (STATS) { s += v; q = fmaf(v, v, q); }
            }
            if (STATS) {
                #pragma unroll
                for (int m = 1; m < 16; m <<= 1) {
                    s += __shfl_xor(s, m);
                    q += __shfl_xor(q, m);
                }
                if (l15 == 0) { sS[wv][co_l] = s; sQ[wv][co_l] = q; }
            }
        }
    }
    if (STATS) {
        __syncthreads();
        if (tid < 32) {
            float s = sS[0][tid] + sS[1][tid] + sS[2][tid] + sS[3][tid];
            float q = sQ[0][tid] + sQ[1][tid] + sQ[2][tid] + sQ[3][tid];
            psum[(cg * 32 + tid) * 256 + n * 4 + pxb] = s;
            pss [(cg * 32 + tid) * 256 + n * 4 + pxb] = q;
        }
    }
}

// ================= MFMA conv1x1 64->64 @32x32, bf16 (decoder) =================
template<int ACT, int STATS>
__global__ void __launch_bounds__(256) mfma_conv1x1_k(
    const unsigned short* __restrict__ inT, const float* __restrict__ w,
    const float* __restrict__ bias, float* __restrict__ out,
    float* __restrict__ psum, float* __restrict__ pss)
{
    __shared__ unsigned short lin[256][72];
    __shared__ unsigned short lwA[32][72];
    __shared__ float sS[4][32], sQ[4][32];
    int b = blockIdx.x;
    int cg = b & 1, pxb = (b >> 1) & 3, n = b >> 3;
    int tid = threadIdx.x;
    int wv = tid >> 6, l = tid & 63;
    int l15 = l & 15, lhi = l >> 4;

    for (int i = tid; i < 2048; i += 256) {
        int px = i >> 3, q = i & 7;
        uint4 v = *(const uint4*)(inT + ((((size_t)n << 10) + pxb * 256 + px) << 6) + q * 8);
        *(uint4*)&lin[px][q * 8] = v;
    }
    for (int i = tid; i < 2048; i += 256) {
        int col = i >> 6, ci = i & 63;
        lwA[col][ci] = f2bf(w[(cg * 32 + col) * 64 + ci]);
    }
    __syncthreads();

    f32x4 acc[2][4];
    #pragma unroll
    for (int ct = 0; ct < 2; ++ct)
        #pragma unroll
        for (int bt = 0; bt < 4; ++bt) {
            f32x4 z = {0.f, 0.f, 0.f, 0.f};
            acc[ct][bt] = z;
        }

    #pragma unroll
    for (int ks = 0; ks < 2; ++ks) {
        short8 a[2], bb[4];
        #pragma unroll
        for (int ct = 0; ct < 2; ++ct)
            a[ct] = *(const short8*)&lwA[ct * 16 + l15][ks * 32 + lhi * 8];
        #pragma unroll
        for (int bt = 0; bt < 4; ++bt)
            bb[bt] = *(const short8*)&lin[wv * 64 + bt * 16 + l15][ks * 32 + lhi * 8];
        #pragma unroll
        for (int ct = 0; ct < 2; ++ct)
            #pragma unroll
            for (int bt = 0; bt < 4; ++bt)
                acc[ct][bt] = __builtin_amdgcn_mfma_f32_16x16x32_bf16(a[ct], bb[bt], acc[ct][bt], 0, 0, 0);
    }

    #pragma unroll
    for (int ct = 0; ct < 2; ++ct) {
        #pragma unroll
        for (int j = 0; j < 4; ++j) {
            int co_l = ct * 16 + lhi * 4 + j;
            int co = cg * 32 + co_l;
            float bv = bias ? bias[co] : 0.f;
            float s = 0.f, q = 0.f;
            #pragma unroll
            for (int bt = 0; bt < 4; ++bt) {
                float v = acc[ct][bt][j] + bv;
                if (ACT == 1) v = lrelu(v);
                int px = pxb * 256 + wv * 64 + bt * 16 + l15;
                out[(((size_t)n * 64 + co) << 10) + px] = v;
                if (STATS) { s += v; q = fmaf(v, v, q); }
            }
            if (STATS) {
                #pragma unroll
                for (int m = 1; m < 16; m <<= 1) {
                    s += __shfl_xor(s, m);
                    q += __shfl_xor(q, m);
                }
                if (l15 == 0) { sS[wv][co_l] = s; sQ[wv][co_l] = q; }
            }
        }
    }
    if (STATS) {
        __syncthreads();
        if (tid < 32) {
            float s = sS[0][tid] + sS[1][tid] + sS[2][tid] + sS[3][tid];
            float q = sQ[0][tid] + sQ[1][tid] + sQ[2][tid] + sQ[3][tid];
            psum[(cg * 32 + tid) * 256 + n * 4 + pxb] = s;
            pss [(cg * 32 + tid) * 256 + n * 4 + pxb] = q;
        }
    }
}

// ================= MFMA dt1: deconv 64->32, 32x32 -> 64x64, lrelu (bf16) =================
__global__ void __launch_bounds__(256) mfma_dt1_k(
    const unsigned short* __restrict__ inT, const float* __restrict__ w,
    const float* __restrict__ bias, float* __restrict__ out)
{
    __shared__ unsigned short lin[5][34][40];
    __shared__ unsigned short lwA[2][32][136];
    int b = blockIdx.x;
    int ublk = b & 7, p_y = (b >> 3) & 1, n = b >> 4;
    int tid = threadIdx.x;
    int wv = tid >> 6, l = tid & 63;
    int l15 = l & 15, lhi = l >> 4;
    int pq = wv & 1;
    int vbase = 1 - pq;
    int ubase = ublk * 4 + (p_y == 0 ? 1 : 0);

    f32x4 acc[2][4];
    #pragma unroll
    for (int ct = 0; ct < 2; ++ct)
        #pragma unroll
        for (int bt = 0; bt < 4; ++bt) {
            f32x4 z = {0.f, 0.f, 0.f, 0.f};
            acc[ct][bt] = z;
        }

    for (int ch = 0; ch < 2; ++ch) {
        __syncthreads();
        for (int i = tid; i < 680; i += 256) {
            int rr = i / 136, rem = i % 136;
            int jc = rem >> 2, q = rem & 3;
            int gy = ubase - 1 + rr, gx = jc - 1;
            uint4 v = make_uint4(0u, 0u, 0u, 0u);
            if (gy >= 0 && gy < 32 && gx >= 0 && gx < 32)
                v = *(const uint4*)(inT + ((((size_t)n << 10) + gy * 32 + gx) << 6) + ch * 32 + q * 8);
            *(uint4*)&lin[rr][jc][q * 8] = v;
        }
        for (int i = tid; i < 8192; i += 256) {
            int pqq = i >> 12, co = (i >> 7) & 31, k = i & 127;
            int tap = k >> 5, cc = k & 31;
            int ci = ch * 32 + cc;
            int ky = p_y + 2 * (tap >> 1), kx = pqq + 2 * (tap & 1);
            lwA[pqq][co][k] = f2bf(w[((ci * 32 + co) << 4) + ky * 4 + kx]);
        }
        __syncthreads();
        #pragma unroll
        for (int ks = 0; ks < 4; ++ks) {
            int ty = ks >> 1, tx = ks & 1;
            short8 a[2], bb[4];
            #pragma unroll
            for (int ct = 0; ct < 2; ++ct)
                a[ct] = *(const short8*)&lwA[pq][ct * 16 + l15][ks * 32 + lhi * 8];
            #pragma unroll
            for (int bt = 0; bt < 4; ++bt) {
                int jloc = (wv >> 1) * 2 + (bt >> 1);
                int vloc = (bt & 1) * 16 + l15;
                bb[bt] = *(const short8*)&lin[jloc + 1 - ty][vloc + vbase + 1 - tx][lhi * 8];
            }
            #pragma unroll
            for (int ct = 0; ct < 2; ++ct)
                #pragma unroll
                for (int bt = 0; bt < 4; ++bt)
                    acc[ct][bt] = __builtin_amdgcn_mfma_f32_16x16x32_bf16(a[ct], bb[bt], acc[ct][bt], 0, 0, 0);
        }
    }

    #pragma unroll
    for (int ct = 0; ct < 2; ++ct) {
        #pragma unroll
        for (int j = 0; j < 4; ++j) {
            int co = ct * 16 + lhi * 4 + j;
            float bv = bias[co];
            #pragma unroll
            for (int bt = 0; bt < 4; ++bt) {
                int jloc = (wv >> 1) * 2 + (bt >> 1);
                int vloc = (bt & 1) * 16 + l15;
                int oy = 2 * (ubase + jloc) - 1 + p_y;
                int ox = 2 * (vloc + vbase) - 1 + pq;
                out[((size_t)(n * 32 + co) << 12) + oy * 64 + ox] = lrelu(acc[ct][bt][j] + bv);
            }
        }
    }
}

// ================= VQ =================
__device__ __forceinline__ unsigned order_u32(float s) {
    unsigned u = __float_as_uint(s);
    return (s < 0.f) ? ~u : (u | 0x80000000u);
}

__global__ void __launch_bounds__(256) vq_dist_k(
    const float* __restrict__ z, const float* __restrict__ emb,
    unsigned long long* __restrict__ best)
{
    __shared__ float se[64][64];
    __shared__ float sn[64];
    int b = blockIdx.x;
    int kb = b & 7, pg = b >> 3;
    int tid = threadIdx.x;
    for (int i = tid; i < 4096; i += 256)
        ((float*)se)[i] = emb[(kb << 12) + i];
    if (tid < 64) {
        const float4* e4 = (const float4*)(emb + (((kb << 6) + tid) << 6));
        float s = 0.f;
        #pragma unroll
        for (int j = 0; j < 16; ++j) {
            float4 e = e4[j];
            s = fmaf(e.x, e.x, s); s = fmaf(e.y, e.y, s);
            s = fmaf(e.z, e.z, s); s = fmaf(e.w, e.w, s);
        }
        sn[tid] = s;
    }
    __syncthreads();

    int n = pg >> 1;
    int p0 = ((pg & 1) << 9) + tid;
    size_t base0 = (size_t)n * 65536 + p0;
    float z0[64], z1[64];
    #pragma unroll
    for (int d = 0; d < 64; ++d) z0[d] = z[base0 + (size_t)d * 1024];
    #pragma unroll
    for (int d = 0; d < 64; ++d) z1[d] = z[base0 + 256 + (size_t)d * 1024];

    unsigned long long b0 = ~0ULL, b1 = ~0ULL;
    for (int k = 0; k < 64; ++k) {
        const float4* e4 = (const float4*)se[k];
        float dot0 = 0.f, dot1 = 0.f;
        #pragma unroll
        for (int j = 0; j < 16; ++j) {
            float4 e = e4[j];
            dot0 = fmaf(z0[4*j],   e.x, dot0);
            dot0 = fmaf(z0[4*j+1], e.y, dot0);
            dot0 = fmaf(z0[4*j+2], e.z, dot0);
            dot0 = fmaf(z0[4*j+3], e.w, dot0);
            dot1 = fmaf(z1[4*j],   e.x, dot1);
            dot1 = fmaf(z1[4*j+1], e.y, dot1);
            dot1 = fmaf(z1[4*j+2], e.z, dot1);
            dot1 = fmaf(z1[4*j+3], e.w, dot1);
        }
        float s0 = fmaf(-2.f, dot0, sn[k]);
        float s1 = fmaf(-2.f, dot1, sn[k]);
        unsigned kk = (unsigned)((kb << 6) + k);
        unsigned long long p0k = ((unsigned long long)order_u32(s0) << 32) | kk;
        unsigned long long p1k = ((unsigned long long)order_u32(s1) << 32) | kk;
        b0 = p0k < b0 ? p0k : b0;
        b1 = p1k < b1 ? p1k : b1;
    }
    size_t m0 = ((size_t)pg << 9) + tid;
    best[((size_t)kb << 16) + m0]       = b0;
    best[((size_t)kb << 16) + m0 + 256] = b1;
}

__global__ void __launch_bounds__(256) vq_combine_k(
    const float* __restrict__ z, const float* __restrict__ emb,
    const unsigned long long* __restrict__ best,
    float* __restrict__ out_q, unsigned short* __restrict__ outT,
    float* __restrict__ partials)
{
    __shared__ unsigned tq32[256][33];
    __shared__ float sh[256];
    int tid = threadIdx.x;
    int m = blockIdx.x * 256 + tid;
    unsigned long long bb = best[m];
    #pragma unroll
    for (int kb = 1; kb < 8; ++kb) {
        unsigned long long v = best[((size_t)kb << 16) + m];
        bb = v < bb ? v : bb;
    }
    int bi = (int)(bb & 0x1ffu);
    int n = m >> 10, p = m & 1023;
    size_t base = (size_t)n * 65536 + p;
    const float* eb = emb + (bi << 6);
    float lsum = 0.f;
    #pragma unroll
    for (int d = 0; d < 64; d += 2) {
        float z0 = z[base + (size_t)d * 1024];
        float z1 = z[base + (size_t)(d + 1) * 1024];
        float q0 = eb[d], q1 = eb[d + 1];
        out_q[base + (size_t)d * 1024]       = q0;
        out_q[base + (size_t)(d + 1) * 1024] = q1;
        float d0 = q0 - z0, d1 = q1 - z1;
        lsum = fmaf(d0, d0, lsum);
        lsum = fmaf(d1, d1, lsum);
        tq32[tid][d >> 1] = (unsigned)f2bf(q0) | ((unsigned)f2bf(q1) << 16);
    }
    sh[tid] = lsum;
    __syncthreads();
    unsigned* oT = (unsigned*)outT;
    size_t m0 = (size_t)blockIdx.x * 256;
    #pragma unroll
    for (int k = 0; k < 32; ++k) {
        int j = k * 256 + tid;
        int px = j >> 5, c = j & 31;
        oT[(m0 + px) * 32 + c] = tq32[px][c];
    }
    for (int st = 128; st > 0; st >>= 1) {
        if (tid < st) sh[tid] += sh[tid + st];
        __syncthreads();
    }
    if (tid == 0) partials[blockIdx.x] = sh[0];
}

__global__ void vq_fin_k(const float* __restrict__ partials, float* __restrict__ out)
{
    __shared__ float sh[256];
    sh[threadIdx.x] = partials[threadIdx.x];
    __syncthreads();
    for (int st = 128; st > 0; st >>= 1) {
        if (threadIdx.x < st) sh[threadIdx.x] += sh[threadIdx.x + st];
        __syncthreads();
    }
    if (threadIdx.x == 0) out[0] = sh[0] * (0.25f / (65536.f * 64.f));
}

// ================= dt2: deconv 32->3, 64x64 -> 128x128, tanh (fp32) =================
__global__ void __launch_bounds__(256) deconv_dt2_t(
    const float* __restrict__ in, const float* __restrict__ w,
    const float* __restrict__ bias, float* __restrict__ out)
{
    __shared__ float lin[8][4][67];
    __shared__ float lw[8][3][16];
    int b = blockIdx.x;
    int n = b & 63, rt = b >> 6;
    int tid = threadIdx.x;
    int r4 = tid >> 6, g = tid & 63;
    int oy = rt * 4 + r4;
    const float* inp = in + (size_t)n * 32 * 4096;
    int iy0 = 2 * rt - 1;
    int ky0 = (oy + 1) & 1;
    int iyA = ((oy + 1 - ky0) >> 1) - iy0;
    int iyB = iyA - 1;

    if (tid < 64) lin[tid >> 3][(tid >> 1) & 3][(tid & 1) ? 65 : 0] = 0.f;

    float acc[3][2];
    #pragma unroll
    for (int co = 0; co < 3; ++co) { acc[co][0] = acc[co][1] = 0.f; }

    int scol = tid & 63, srs = tid >> 6;
    for (int cic = 0; cic < 4; ++cic) {
        __syncthreads();
        {
            int gy = iy0 + srs;
            bool ok = (gy >= 0 && gy < 64);
            #pragma unroll
            for (int k = 0; k < 8; ++k) {
                float v = ok ? inp[(cic * 8 + k) * 4096 + gy * 64 + scol] : 0.f;
                lin[k][srs][scol + 1] = v;
            }
        }
        if (tid < 128) {
            int ci = tid >> 4, tt = tid & 15;
            #pragma unroll
            for (int co = 0; co < 3; ++co)
                lw[ci][co][tt] = w[((cic * 8 + ci) * 3 + co) * 16 + tt];
        }
        __syncthreads();
        #pragma unroll 2
        for (int ci = 0; ci < 8; ++ci) {
            float vA0 = lin[ci][iyA][g],     vA1 = lin[ci][iyA][g + 1], vA2 = lin[ci][iyA][g + 2];
            float vB0 = lin[ci][iyB][g],     vB1 = lin[ci][iyB][g + 1], vB2 = lin[ci][iyB][g + 2];
            #pragma unroll
            for (int co = 0; co < 3; ++co) {
                const float4* wp = (const float4*)lw[ci][co];
                float4 wA = wp[ky0];
                float4 wB = wp[ky0 + 2];
                acc[co][0] = fmaf(vA1, wA.y, fmaf(vA0, wA.w, fmaf(vB1, wB.y, fmaf(vB0, wB.w, acc[co][0]))));
                acc[co][1] = fmaf(vA2, wA.x, fmaf(vA1, wA.z, fmaf(vB2, wB.x, fmaf(vB1, wB.z, acc[co][1]))));
            }
        }
    }
    #pragma unroll
    for (int co = 0; co < 3; ++co) {
        float bv = bias[co];
        float2 v;
        v.x = fast_tanh(acc[co][0] + bv);
        v.y = fast_tanh(acc[co][1] + bv);
        *(float2*)(out + ((size_t)(n * 3 + co) * 16384) + oy * 128 + 2 * g) = v;
    }
}

extern "C" void kernel_launch(void* const* d_in, const int* in_sizes, int n_in,
                              void* d_out, int out_size, void* d_ws, size_t ws_size,
                              hipStream_t stream)
{
    const float* x    = (const float*)d_in[0];
    const float* e1w  = (const float*)d_in[1];
    const float* e1b  = (const float*)d_in[2];
    const float* e2w  = (const float*)d_in[3];
    const float* e2b  = (const float*)d_in[4];
    const float* e3w  = (const float*)d_in[5];
    const float* e3b  = (const float*)d_in[6];
    const float* er1w = (const float*)d_in[7];
    const float* er1g = (const float*)d_in[8];
    const float* er1b = (const float*)d_in[9];
    const float* er2w = (const float*)d_in[10];
    const float* er2g = (const float*)d_in[11];
    const float* er2b = (const float*)d_in[12];
    const float* e4w  = (const float*)d_in[13];
    const float* e4b  = (const float*)d_in[14];
    const float* emb  = (const float*)d_in[15];
    const float* d1w  = (const float*)d_in[16];
    const float* d1b  = (const float*)d_in[17];
    const float* dr1w = (const float*)d_in[18];
    const float* dr1g = (const float*)d_in[19];
    const float* dr1b = (const float*)d_in[20];
    const float* dr2w = (const float*)d_in[21];
    const float* dr2g = (const float*)d_in[22];
    const float* dr2b = (const float*)d_in[23];
    const float* dt1w = (const float*)d_in[24];
    const float* dt1b = (const float*)d_in[25];
    const float* dt2w = (const float*)d_in[26];
    const float* dt2b = (const float*)d_in[27];

    float* out = (float*)d_out;
    float* ws  = (float*)d_ws;

    // workspace layout (floats)
    float* B0 = ws;                   // 8,388,608
    float* B1 = ws + 8388608;         // 4,194,304
    float* B2 = B1 + 4194304;
    float* B3 = B2 + 4194304;
    float* B4 = B3 + 4194304;
    float* psum   = B4 + 4194304;     // 16384
    float* pss    = psum + 16384;     // 16384
    float* fin    = pss + 16384;      // 128
    float* vq_part = fin + 128;       // 256
    float* enorm   = vq_part + 256;   // 512 (unused)
    unsigned long long* bestbuf = (unsigned long long*)(enorm + 512);  // 4MB

    unsigned short* tbuf  = (unsigned short*)B1;  // decoder NHWC bf16
    unsigned short* tbufH = (unsigned short*)B3;  // encoder split-bf16 hi
    unsigned short* tbufL = (unsigned short*)B4;  // encoder split-bf16 lo

    float* out_recon = out;                 // 3,145,728
    float* out_q     = out + 3145728;       // 4,194,304
    float* out_e     = out + 7340032;       // 4,194,304 (scratch until e4 writes)
    float* out_loss  = out + 11534336;      // 1

    const float invM = 1.f / 65536.f;

    // ---------------- encoder ----------------
    conv_e1_t<<<1024, 256, 0, stream>>>(x, e1w, e1b, B0);
    conv_e2p_k<<<1024, 256, 0, stream>>>(B0, e2w, B1, out_e);

    // e3 = conv3x3(lrelu(e2pA + e2pB + e2b)) via split-bf16 MFMA
    trans_hl_k<1><<<256, 256, 0, stream>>>(B1, out_e, e2b, tbufH, tbufL);
    mfma_conv3x3_hl_k<1,0><<<512, 256, 0, stream>>>(tbufH, tbufL, e3w, e3b, B2, nullptr, nullptr);

    // er1 = conv3x3(B2), no act, + BN stats
    trans_hl_k<0><<<256, 256, 0, stream>>>(B2, nullptr, nullptr, tbufH, tbufL);
    mfma_conv3x3_hl_k<0,1><<<512, 256, 0, stream>>>(tbufH, tbufL, er1w, nullptr, B1, psum, pss);
    bn_fin3_k<<<1, 64, 0, stream>>>(psum, pss, fin, invM);

    conv1x1_t<1,0,1><<<512, 256, 0, stream>>>(B1, nullptr, er2w, nullptr, fin, er1g, er1b, B4, psum, pss);
    bn_fin2_k<<<1, 64, 0, stream>>>(psum, pss, fin, invM, 64);
    conv1x1_t<2,1,0><<<512, 256, 0, stream>>>(B4, B2, e4w, e4b, fin, er2g, er2b, out_e, nullptr, nullptr);

    // VQ (fp32); combine emits NHWC bf16 tbuf for the decoder
    vq_dist_k<<<1024, 256, 0, stream>>>(out_e, emb, bestbuf);
    vq_combine_k<<<256, 256, 0, stream>>>(out_e, emb, bestbuf, out_q, tbuf, vq_part);
    vq_fin_k<<<1, 256, 0, stream>>>(vq_part, out_loss);

    // ---------------- decoder (bf16 MFMA) ----------------
    mfma_conv3x3_k<1,0><<<512, 256, 0, stream>>>(tbuf, d1w, d1b, B2, nullptr, nullptr);

    trans_k<0><<<256, 256, 0, stream>>>(B2, nullptr, nullptr, nullptr, tbuf);
    mfma_conv3x3_k<0,1><<<512, 256, 0, stream>>>(tbuf, dr1w, nullptr, B3, psum, pss);
    bn_fin3_k<<<1, 64, 0, stream>>>(psum, pss, fin, invM);

    trans_k<1><<<256, 256, 0, stream>>>(B3, fin, dr1g, dr1b, tbuf);
    mfma_conv1x1_k<0,1><<<512, 256, 0, stream>>>(tbuf, dr2w, nullptr, B4, psum, pss);
    bn_fin3_k<<<1, 64, 0, stream>>>(psum, pss, fin, invM);

    bnres_trans_k<<<256, 256, 0, stream>>>(B4, B2, fin, dr2g, dr2b, tbuf);
    mfma_dt1_k<<<1024, 256, 0, stream>>>(tbuf, dt1w, dt1b, B0);

    deconv_dt2_t<<<2048, 256, 0, stream>>>(B0, dt2w, dt2b, out_recon);
}